// Round 5
// baseline (288.577 us; speedup 1.0000x reference)
//
#include <hip/hip_runtime.h>
#include <math.h>

#define CDIM 384
#define NHEADS 8
#define HD 48
#define NQ 784      // 28*28 pooled tokens
#define NQPAD 832   // 13*64, zero-padded k/n extent for V^T
#define NB 16
#define HWD 56
#define NPIX 3136   // 56*56
// 48^-0.5 * log2(e): scores land in exp2 domain, softmax uses raw v_exp_f32
#define QK_SCALE (0.14433756729740643f * 1.4426950408889634f)
#define LN_EPS 1e-5f
#define WSCALE 16.0f     // fold into W_pq to stay clear of f16 denormals
#define WUNSCALE 0.0625f

typedef _Float16 f16;
typedef _Float16 f16x4 __attribute__((ext_vector_type(4)));
typedef _Float16 f16x8 __attribute__((ext_vector_type(8)));
typedef float f32x4 __attribute__((ext_vector_type(4)));

// ---------------- wave/block reduction helpers ----------------
__device__ __forceinline__ float waveSum(float v) {
#pragma unroll
  for (int o = 32; o > 0; o >>= 1) v += __shfl_xor(v, o);
  return v;
}

__device__ __forceinline__ float fast_exp2(float x) {
#if __has_builtin(__builtin_amdgcn_exp2f)
  return __builtin_amdgcn_exp2f(x);
#else
  return __expf(x * 0.6931471805599453f);
#endif
}

// async global->LDS 16B copy (wave-uniform lds base + lane*16 scatter)
__device__ __forceinline__ void gload16(const void* g, void* l) {
  __builtin_amdgcn_global_load_lds(
      (const __attribute__((address_space(1))) void*)g,
      (__attribute__((address_space(3))) void*)l, 16, 0, 0);
}

// chunked-bijective XCD swizzle (m204): dispatch id b -> linear tile id such
// that blocks resident on one XCD (b%8 round-robin) cover a contiguous chunk
// of tiles -> per-XCD L2 working set stays small.
__device__ __forceinline__ int xcd_chunk_lin(int b, int nwg) {
  const int c = b & 7, s = b >> 3;
  const int q = nwg >> 3, r = nwg & 7;
  const int off = (c < r) ? c * (q + 1) : r * (q + 1) + (c - r) * q;
  return off + s;
}

// ---------------- zero workspace region ----------------
__global__ __launch_bounds__(256) void zero_kernel(float4* __restrict__ p,
                                                   int n4) {
  const int i = blockIdx.x * 256 + threadIdx.x;
  if (i < n4) p[i] = make_float4(0.f, 0.f, 0.f, 0.f);
}

// ---------------- cast kernels ----------------
// pooled-gather x -> fp16 A matrix [12544, 384]
__global__ __launch_bounds__(256) void pool_cast_kernel(
    const float* __restrict__ x, f16* __restrict__ xp) {
  const int i = (blockIdx.x * 256 + threadIdx.x) * 4;  // < 12544*384, %4==0
  const int row = i / CDIM, col = i % CDIM;
  const int b = row / NQ, qi = row % NQ;
  const int hi = qi / 28, wi = qi % 28;
  const float4 v =
      *(const float4*)(x + ((size_t)(b * NPIX + hi * 112 + wi * 2)) * CDIM + col);
  f16x4 h;
  h.x = (f16)v.x; h.y = (f16)v.y; h.z = (f16)v.z; h.w = (f16)v.w;
  *(f16x4*)(xp + i) = h;
}

__global__ __launch_bounds__(256) void w_cast_kernel(
    const float* __restrict__ src, f16* __restrict__ dst, int n) {
  const int i = (blockIdx.x * 256 + threadIdx.x) * 4;
  if (i >= n) return;
  const float4 v = *(const float4*)(src + i);
  f16x4 h;
  h.x = (f16)v.x; h.y = (f16)v.y; h.z = (f16)v.z; h.w = (f16)v.w;
  *(f16x4*)(dst + i) = h;
}

// ---------------- full-K LDS-resident MFMA tile GEMM ----------------
// Block computes C(64m x 128n) = A[M,384] @ B[N,384]^T with the ENTIRE
// K=384 of the A-tile (48 KB) and B-panel (96 KB) staged to LDS in one
// phase -> ONE barrier, then 96 straight-line MFMAs/wave, no inner syncs.
// LDS rows are linear 768B (global_load_lds needs dest = base + unit*16,
// which holds exactly since 384*2 = 48*16). Bank-conflict fix per rule 21:
// the 16B chunk index is XOR-swizzled (chunk ^ (row&7)) on the GLOBAL
// source address at stage time and identically on the fragment read.
__device__ __forceinline__ void mfma_fullk_gemm(
    const f16* __restrict__ A, const f16* __restrict__ B, int m0, int n0,
    f32x4 (&acc)[2][4], f16* As /*64x384*/, f16* Bs /*128x384*/) {
  const int t = threadIdx.x;
  const int lane = t & 63, w = t >> 6;
  const int wm = w >> 1, wn = w & 1;
  const int l15 = lane & 15, l4 = lane >> 4;
  const char* Ag = (const char*)A;
  const char* Bg = (const char*)B;
  char* AsB = (char*)As;
  char* BsB = (char*)Bs;

  // stage: 9216 16B-units (A: 3072, B: 6144) = 36 per thread.
  // c<12 is all-A, c>=12 all-B (boundary 3072 = 12*256, wave-aligned).
#pragma unroll
  for (int c = 0; c < 36; ++c) {
    const int u = t + c * 256;
    if (c < 12) {
      const int row = u / 48, seg = u % 48;
      gload16(Ag + (((size_t)(m0 + row) * 384 + (seg ^ (row & 7)) * 8) * 2),
              AsB + u * 16);
    } else {
      const int v = u - 3072;
      const int row = v / 48, seg = v % 48;
      gload16(Bg + (((size_t)(n0 + row) * 384 + (seg ^ (row & 7)) * 8) * 2),
              BsB + v * 16);
    }
  }
  __syncthreads();

#pragma unroll
  for (int ks = 0; ks < 12; ++ks) {
    const int c0 = ks * 4;
    f16x8 af[2], bf[4];
#pragma unroll
    for (int i = 0; i < 2; ++i) {
      const int row = wm * 32 + i * 16 + l15;
      const int ch = (c0 + l4) ^ (row & 7);
      af[i] = *(const f16x8*)(AsB + row * 768 + ch * 16);
    }
#pragma unroll
    for (int j = 0; j < 4; ++j) {
      const int row = wn * 64 + j * 16 + l15;
      const int ch = (c0 + l4) ^ (row & 7);
      bf[j] = *(const f16x8*)(BsB + row * 768 + ch * 16);
    }
#pragma unroll
    for (int i = 0; i < 2; ++i)
#pragma unroll
      for (int j = 0; j < 4; ++j)
        acc[i][j] =
            __builtin_amdgcn_mfma_f32_16x16x32_f16(af[i], bf[j], acc[i][j], 0, 0, 0);
  }
}

// ---------------- Kernel A: QKV GEMM (fp16 MFMA, full-K LDS) ----------------
// 1D grid 1764 = 196 m-tiles(64) x 9 n-tiles(128), XCD-chunk swizzled.
// Writes q scaled fp16 [bh][n][64]pad, k fp16 [bh][n][64]pad, v^T fp16 [bh][d][832]pad
__global__ __launch_bounds__(256) void qkv_mfma_kernel(
    const f16* __restrict__ xp, const f16* __restrict__ wh,
    const float* __restrict__ qkv_b, f16* __restrict__ qh,
    f16* __restrict__ kh, f16* __restrict__ vt) {
  __shared__ f16 As[64 * 384];    // 48 KB
  __shared__ f16 Bs[128 * 384];   // 96 KB
  const int lin = xcd_chunk_lin(blockIdx.x, 1764);
  const int m0 = (lin / 9) * 64, n0 = (lin % 9) * 128;
  f32x4 acc[2][4] = {};
  mfma_fullk_gemm(xp, wh, m0, n0, acc, As, Bs);

  const int t = threadIdx.x, lane = t & 63, w = t >> 6;
  const int wm = w >> 1, wn = w & 1;
  const int l15 = lane & 15, l4 = lane >> 4;
#pragma unroll
  for (int j = 0; j < 4; ++j) {
    const int f = n0 + wn * 64 + j * 16 + l15;
    const int sec = f / CDIM, fr = f % CDIM;
    const int hh = fr / HD, d = fr % HD;
    const float bias = qkv_b[f];
#pragma unroll
    for (int i = 0; i < 2; ++i) {
#pragma unroll
      for (int r = 0; r < 4; ++r) {
        const int mm = m0 + wm * 32 + i * 16 + l4 * 4 + r;
        const int bb = mm / NQ, qi = mm % NQ;
        const int bh = bb * NHEADS + hh;
        const float val = acc[i][j][r] + bias;
        if (sec == 0)
          qh[((size_t)bh * NQ + qi) * 64 + d] = (f16)(val * QK_SCALE);
        else if (sec == 1)
          kh[((size_t)bh * NQ + qi) * 64 + d] = (f16)val;
        else
          vt[((size_t)bh * HD + d) * NQPAD + qi] = (f16)val;
      }
    }
  }
}

// ---------------- Kernel B: fused flash attention (no-max softmax) ----------------
// 128 q-rows per block. QK^T runs k=0..63 with LDS-zeroed pad cols 48..63
// (two chained 16x16x32 MFMAs); only the 48 real cols are staged from HBM.
// Q fragments hoisted to regs so Qs LDS is recycled as the Ps buffer; Ps
// stride 68 keeps the scalar P stores spread; K/V staging is reg-prefetched.
__global__ __launch_bounds__(256) void flash_kernel(
    const f16* __restrict__ qh, const f16* __restrict__ kh,
    const f16* __restrict__ vt, f16* __restrict__ o16) {
  __shared__ f16 PQ[128 * 72];     // 18432 B: Qs[128][72]; recycled as Ps[4][32][68]
  __shared__ f16 Ks[64][72];       // 9216 B
  __shared__ f16 Vts[48][72];      // 6912 B

  f16 (*Qs)[72] = (f16(*)[72])PQ;
  f16 (*Ps)[32][68] = (f16(*)[32][68])PQ;

  const int t = threadIdx.x;
  const int lane = t & 63, w = t >> 6;
  const int quad = lane >> 4, l15 = lane & 15;
  const int q0 = blockIdx.x * 128;
  const int bh = blockIdx.y;

  const f16* qg = qh + (size_t)bh * NQ * 64;
  const f16* kg = kh + (size_t)bh * NQ * 64;
  const f16* vg = vt + (size_t)bh * HD * NQPAD;

  // ---- zero k-pad cols 48..63 of Qs (256 units) and Ks (128 units) ----
  {
    const f16x8 z8 = {};
    *(f16x8*)&Qs[t >> 1][48 + (t & 1) * 8] = z8;
    if (t < 128) *(f16x8*)&Ks[t >> 1][48 + (t & 1) * 8] = z8;
  }

  // ---- stage Q tile: 128 rows x 48 cols (6 segs of 16B) ----
#pragma unroll
  for (int c = 0; c < 3; ++c) {
    const int u = t + c * 256;  // < 768
    const int row = u / 6, seg = u % 6;
    const int gr = min(q0 + row, NQ - 1);
    *(f16x8*)&Qs[row][seg * 8] =
        *(const f16x8*)(qg + (size_t)gr * 64 + seg * 8);
  }
  __syncthreads();

  // ---- hoist Q fragments (Qs LDS is recycled as Ps after this) ----
  f16x8 qf0[2], qf1[2];
#pragma unroll
  for (int qa = 0; qa < 2; ++qa) {
    const int row = w * 32 + qa * 16 + l15;
    qf0[qa] = *(const f16x8*)&Qs[row][quad * 8];
    qf1[qa] = *(const f16x8*)&Qs[row][32 + quad * 8];
  }

  // ---- staging plan: 768 16B-units per K/V tile = 3 per thread ----
  const f16* gp[3];
  f16* lp[3];
  int step[3];
#pragma unroll
  for (int c = 0; c < 3; ++c) {
    const int u = t + c * 256;
    if (u < 384) {  // K: 64 rows x 6 segs (cols 0..47)
      const int row = u / 6, seg = u % 6;
      gp[c] = kg + (size_t)row * 64 + seg * 8;
      lp[c] = &Ks[row][seg * 8];
      step[c] = 64 * 64;
    } else {        // V^T: 48 rows x 8 segs
      const int uv = u - 384;
      const int row = uv >> 3, seg = uv & 7;
      gp[c] = vg + (size_t)row * NQPAD + seg * 8;
      lp[c] = &Vts[row][seg * 8];
      step[c] = 64;
    }
  }

  // prologue: issue tile 0 loads
  f16x8 rg[3];
#pragma unroll
  for (int c = 0; c < 3; ++c) {
    rg[c] = *(const f16x8*)gp[c];
    gp[c] += step[c];
  }

  f32x4 accO[2][3] = {};
  float l_[2][4] = {};

  for (int kt = 0; kt < 13; ++kt) {
    // commit staged tile kt to LDS (cols 0..47 only; pads stay zero)
#pragma unroll
    for (int c = 0; c < 3; ++c) *(f16x8*)lp[c] = rg[c];
    __syncthreads();
    // issue tile kt+1 loads; HBM latency hides under compute below
    if (kt < 12) {
#pragma unroll
      for (int c = 0; c < 3; ++c) {
        rg[c] = *(const f16x8*)gp[c];
        gp[c] += step[c];
      }
    }

    // ---- QK^T (k=0..63, pad zeros) fused with exp2 + row-sum + P store ----
    const bool last = (kt == 12);
#pragma unroll
    for (int j = 0; j < 4; ++j) {
      const f16x8 b0 = *(const f16x8*)&Ks[j * 16 + l15][quad * 8];
      const f16x8 b1 = *(const f16x8*)&Ks[j * 16 + l15][32 + quad * 8];
      f32x4 z0 = {}, z1 = {};
      z0 = __builtin_amdgcn_mfma_f32_16x16x32_f16(qf0[0], b0, z0, 0, 0, 0);
      const f32x4 sj0 = __builtin_amdgcn_mfma_f32_16x16x32_f16(qf1[0], b1, z0, 0, 0, 0);
      z1 = __builtin_amdgcn_mfma_f32_16x16x32_f16(qf0[1], b0, z1, 0, 0, 0);
      const f32x4 sj1 = __builtin_amdgcn_mfma_f32_16x16x32_f16(qf1[1], b1, z1, 0, 0, 0);
      const bool msk = last && (j >= 1);  // keys >= 784
#pragma unroll
      for (int r = 0; r < 4; ++r) {
        const float p0 = msk ? 0.f : fast_exp2(sj0[r]);
        const float p1 = msk ? 0.f : fast_exp2(sj1[r]);
        l_[0][r] += p0;
        l_[1][r] += p1;
        Ps[w][quad * 4 + r][j * 16 + l15] = (f16)p0;
        Ps[w][16 + quad * 4 + r][j * 16 + l15] = (f16)p1;
      }
    }

    // ---- P fragments (8B-aligned b64 pairs; stride 68 spreads banks) ----
    f16x8 ap0[2], ap1[2];
#pragma unroll
    for (int qa = 0; qa < 2; ++qa) {
      const int row = qa * 16 + l15;
      const f16x4 a0 = *(const f16x4*)&Ps[w][row][quad * 8];
      const f16x4 a1 = *(const f16x4*)&Ps[w][row][quad * 8 + 4];
      const f16x4 a2 = *(const f16x4*)&Ps[w][row][32 + quad * 8];
      const f16x4 a3 = *(const f16x4*)&Ps[w][row][32 + quad * 8 + 4];
      ap0[qa] = __builtin_shufflevector(a0, a1, 0, 1, 2, 3, 4, 5, 6, 7);
      ap1[qa] = __builtin_shufflevector(a2, a3, 0, 1, 2, 3, 4, 5, 6, 7);
    }

    // ---- PV ----
#pragma unroll
    for (int jn = 0; jn < 3; ++jn) {
      const f16x8 v0 = *(const f16x8*)&Vts[jn * 16 + l15][quad * 8];
      const f16x8 v1 = *(const f16x8*)&Vts[jn * 16 + l15][32 + quad * 8];
#pragma unroll
      for (int qa = 0; qa < 2; ++qa) {
        accO[qa][jn] =
            __builtin_amdgcn_mfma_f32_16x16x32_f16(ap0[qa], v0, accO[qa][jn], 0, 0, 0);
        accO[qa][jn] =
            __builtin_amdgcn_mfma_f32_16x16x32_f16(ap1[qa], v1, accO[qa][jn], 0, 0, 0);
      }
    }
    __syncthreads();
  }

  // ---- normalize + store ----
  const int b = bh >> 3, hh = bh & 7;
#pragma unroll
  for (int qa = 0; qa < 2; ++qa) {
#pragma unroll
    for (int r = 0; r < 4; ++r) {
      float rs = l_[qa][r];
      rs += __shfl_xor(rs, 1);
      rs += __shfl_xor(rs, 2);
      rs += __shfl_xor(rs, 4);
      rs += __shfl_xor(rs, 8);
      const int qrow = q0 + w * 32 + qa * 16 + quad * 4 + r;
      if (qrow < NQ) {
        const float inv = 1.f / rs;
#pragma unroll
        for (int jn = 0; jn < 3; ++jn)
          o16[((size_t)(b * NQ + qrow)) * CDIM + hh * HD + jn * 16 + l15] =
              (f16)(accO[qa][jn][r] * inv);
      }
    }
  }
}

// ---------------- Kernel C1: per-row LN stats for the 4 upsample phases ----------------
// u_pq = o * lp_w[:,pq] + lp_b; stats[m][pq] = (mu, rstd). One wave per row.
__global__ __launch_bounds__(256) void stats_kernel(
    const f16* __restrict__ o16, const float* __restrict__ lp_w,
    const float* __restrict__ lp_b, float* __restrict__ stats) {
  const int m = blockIdx.x * 4 + (threadIdx.x >> 6);
  const int lane = threadIdx.x & 63;
  float s[4] = {}, ss[4] = {};
#pragma unroll
  for (int i = 0; i < 6; ++i) {
    const int c = lane + i * 64;
    const float ov = (float)o16[(size_t)m * CDIM + c];
    const float4 w4 = *(const float4*)(lp_w + c * 4);
    const float bb = lp_b[c];
    const float u0 = ov * w4.x + bb;
    const float u1 = ov * w4.y + bb;
    const float u2 = ov * w4.z + bb;
    const float u3 = ov * w4.w + bb;
    s[0] += u0; ss[0] += u0 * u0;
    s[1] += u1; ss[1] += u1 * u1;
    s[2] += u2; ss[2] += u2 * u2;
    s[3] += u3; ss[3] += u3 * u3;
  }
#pragma unroll
  for (int pq = 0; pq < 4; ++pq) {
    s[pq] = waveSum(s[pq]);
    ss[pq] = waveSum(ss[pq]);
  }
  if (lane < 4) {
    const float mu = s[lane] * (1.f / CDIM);
    const float var = ss[lane] * (1.f / CDIM) - mu * mu;
    stats[m * 8 + lane * 2] = mu;
    stats[m * 8 + lane * 2 + 1] = rsqrtf(var + LN_EPS);
  }
}

// ---------------- Kernel C2: W_pq = proj_w * (lp_w[:,pq]*ln_w) * WSCALE -> f16 ----------------
// Layout [f=pq*384+j][c].
__global__ __launch_bounds__(256) void wprep_kernel(
    const float* __restrict__ pw, const float* __restrict__ lpw,
    const float* __restrict__ lnw, f16* __restrict__ wq) {
  const int i4 = (blockIdx.x * 256 + threadIdx.x) * 4;  // < 1536*384
  const int f = i4 / CDIM, c = i4 % CDIM;
  const int pq = f / CDIM, j = f % CDIM;
  const float4 wv = *(const float4*)(pw + (size_t)j * CDIM + c);
  const float4 ln = *(const float4*)(lnw + c);
  f16x4 h;
  h.x = (f16)(wv.x * lpw[(c + 0) * 4 + pq] * ln.x * WSCALE);
  h.y = (f16)(wv.y * lpw[(c + 1) * 4 + pq] * ln.y * WSCALE);
  h.z = (f16)(wv.z * lpw[(c + 2) * 4 + pq] * ln.z * WSCALE);
  h.w = (f16)(wv.w * lpw[(c + 3) * 4 + pq] * ln.w * WSCALE);
  *(f16x4*)(wq + i4) = h;
}

// ---------------- Kernel C3: constant vectors ----------------
// c1[j]=sum_c lp_b*ln_w*W[j][c]; c2[j]=sum_c ln_w*W[j][c]; c3[j]=sum_c ln_b*W[j][c]+pb[j]
__global__ __launch_bounds__(64) void cvec_kernel(
    const float* __restrict__ pw, const float* __restrict__ lp_b,
    const float* __restrict__ ln_w, const float* __restrict__ ln_b,
    const float* __restrict__ pb, float* __restrict__ cvec) {
  const int j = blockIdx.x;
  const int lane = threadIdx.x;
  float a1 = 0.f, a2 = 0.f, a3 = 0.f;
#pragma unroll
  for (int i = 0; i < 6; ++i) {
    const int c = lane + i * 64;
    const float wv = pw[(size_t)j * CDIM + c];
    a1 += lp_b[c] * ln_w[c] * wv;
    a2 += ln_w[c] * wv;
    a3 += ln_b[c] * wv;
  }
  a1 = waveSum(a1);
  a2 = waveSum(a2);
  a3 = waveSum(a3);
  if (lane == 0) {
    cvec[j] = a1;
    cvec[CDIM + j] = a2;
    cvec[2 * CDIM + j] = a3 + pb[j];
  }
}

// ---------------- Kernel D: fused upsample+LN+proj GEMM (full-K LDS) ----------------
// G = o16 @ wq^T  (M=12544, N=1536, K=384); out row (m,pq) -> pixel scatter.
// 1D grid 2352 = 196 m-tiles(64) x 12 n-tiles(128), XCD-chunk swizzled; each
// block's 128-col range lies in exactly one pq (384=3*128).
__global__ __launch_bounds__(256) void projfused_kernel(
    const f16* __restrict__ o16, const f16* __restrict__ wq,
    const float* __restrict__ stats, const float* __restrict__ cvec,
    float* __restrict__ out) {
  __shared__ f16 As[64 * 384];    // 48 KB
  __shared__ f16 Bs[128 * 384];   // 96 KB
  const int lin = xcd_chunk_lin(blockIdx.x, 2352);
  const int m0 = (lin / 12) * 64, n0 = (lin % 12) * 128;
  f32x4 acc[2][4] = {};
  mfma_fullk_gemm(o16, wq, m0, n0, acc, As, Bs);

  const int t = threadIdx.x, lane = t & 63, w = t >> 6;
  const int wm = w >> 1, wn = w & 1;
  const int l15 = lane & 15, l4 = lane >> 4;
  const int pq = n0 / CDIM;  // uniform per block
  const int p = pq >> 1, q = pq & 1;
  const int c0 = n0 - pq * CDIM;

  float C1[4], C2[4], C3[4];
#pragma unroll
  for (int j = 0; j < 4; ++j) {
    const int col = c0 + wn * 64 + j * 16 + l15;
    C1[j] = cvec[col];
    C2[j] = cvec[CDIM + col];
    C3[j] = cvec[2 * CDIM + col];
  }

#pragma unroll
  for (int i = 0; i < 2; ++i) {
#pragma unroll
    for (int r = 0; r < 4; ++r) {
      const int m = m0 + wm * 32 + i * 16 + l4 * 4 + r;
      const int b = m / NQ, n = m % NQ;
      const int hi2 = n / 28, wi2 = n % 28;
      const float mu = stats[m * 8 + pq * 2];
      const float rstd = stats[m * 8 + pq * 2 + 1];
      const int pix = (hi2 * 2 + p) * HWD + (wi2 * 2 + q);
      float* orow = out + ((size_t)(b * NPIX + pix)) * CDIM;
#pragma unroll
      for (int j = 0; j < 4; ++j) {
        const int col = c0 + wn * 64 + j * 16 + l15;
        orow[col] = rstd * (acc[i][j][r] * WUNSCALE + C1[j] - mu * C2[j]) + C3[j];
      }
    }
  }
}

extern "C" void kernel_launch(void* const* d_in, const int* in_sizes, int n_in,
                              void* d_out, int out_size, void* d_ws,
                              size_t ws_size, hipStream_t stream) {
  const float* x      = (const float*)d_in[0];
  const float* qkv_w  = (const float*)d_in[1];
  const float* qkv_b  = (const float*)d_in[2];
  const float* proj_w = (const float*)d_in[3];
  const float* proj_b = (const float*)d_in[4];
  const float* lp_w   = (const float*)d_in[5];
  const float* lp_b   = (const float*)d_in[6];
  const float* ln_w   = (const float*)d_in[7];
  const float* ln_b   = (const float*)d_in[8];
  float* out = (float*)d_out;

  // workspace layout (float offsets), total ~15.3M floats = 61 MB
  float* ws = (float*)d_ws;
  f16* o16 = (f16*)ws;                        // [12544][384]   4,816,896 f16 (2,408,448 fl)
  float* zreg = ws + 2408448;                 // region: qh,kh,vt (only vt needs zeroing)
  f16* qh = (f16*)zreg;                       // [128][784][64] 6,422,528 f16
  f16* kh = qh + (size_t)128 * NQ * 64;       // [128][784][64] 6,422,528 f16
  f16* vt = kh + (size_t)128 * NQ * 64;       // [128][48][832] 5,111,808 f16
  float* rest = zreg + 8978432;               // end of q/k/v region
  f16* xp = (f16*)rest;                       // [12544][384]   4,816,896 f16
  f16* qkv_wh = xp + (size_t)12544 * CDIM;    // [1152][384]      442,368 f16
  float* rest2 = rest + 2408448 + 221184;
  f16* wq = (f16*)rest2;                      // [1536][384]    2,359,296 f16 (1,179,648 fl)
  float* cvec = rest2 + 1179648;              // [3][384]           1,152 fl
  float* stats = cvec + 1152;                 // [12544][4][2]    100,352 fl

  // 0) zero v^T pad tokens (q/k pads are never read anymore)
  zero_kernel<<<dim3(2496), 256, 0, stream>>>((float4*)(zreg + 6422528), 638976);

  // 1) casts + pooled qkv (fp16 MFMA)
  pool_cast_kernel<<<dim3(4704), 256, 0, stream>>>(x, xp);
  w_cast_kernel<<<dim3(432), 256, 0, stream>>>(qkv_w, qkv_wh, 1152 * CDIM);
  qkv_mfma_kernel<<<dim3(1764), 256, 0, stream>>>(xp, qkv_wh, qkv_b, qh, kh, vt);

  // 2) fused flash attention -> fp16 o (128 q-rows/block)
  flash_kernel<<<dim3(7, 128), 256, 0, stream>>>(qh, kh, vt, o16);

  // 3) LN stats + folded weights + constant vectors
  stats_kernel<<<dim3(3136), 256, 0, stream>>>(o16, lp_w, lp_b, stats);
  wprep_kernel<<<dim3(576), 256, 0, stream>>>(proj_w, lp_w, ln_w, wq);
  cvec_kernel<<<dim3(384), 64, 0, stream>>>(proj_w, lp_b, ln_w, ln_b, proj_b,
                                            cvec);

  // 4) fused upsample+LN+proj GEMM
  projfused_kernel<<<dim3(2352), 256, 0, stream>>>(o16, wq, stats, cvec, out);
}

// Round 6
// 254.643 us; speedup vs baseline: 1.1333x; 1.1333x over previous
//
#include <hip/hip_runtime.h>
#include <math.h>

#define CDIM 384
#define NHEADS 8
#define HD 48
#define NQ 784      // 28*28 pooled tokens
#define NQPAD 832   // 13*64, zero-padded k/n extent for V^T
#define NB 16
#define HWD 56
#define NPIX 3136   // 56*56
// 48^-0.5 * log2(e): scores land in exp2 domain, softmax uses raw v_exp_f32
#define QK_SCALE (0.14433756729740643f * 1.4426950408889634f)
#define LN_EPS 1e-5f
#define WSCALE 16.0f     // fold into W_pq to stay clear of f16 denormals
#define WUNSCALE 0.0625f

typedef _Float16 f16;
typedef _Float16 f16x4 __attribute__((ext_vector_type(4)));
typedef _Float16 f16x8 __attribute__((ext_vector_type(8)));
typedef float f32x4 __attribute__((ext_vector_type(4)));

// ---------------- wave/block reduction helpers ----------------
__device__ __forceinline__ float waveSum(float v) {
#pragma unroll
  for (int o = 32; o > 0; o >>= 1) v += __shfl_xor(v, o);
  return v;
}

__device__ __forceinline__ float fast_exp2(float x) {
#if __has_builtin(__builtin_amdgcn_exp2f)
  return __builtin_amdgcn_exp2f(x);
#else
  return __expf(x * 0.6931471805599453f);
#endif
}

// async global->LDS 16B copy (wave-uniform lds base + lane*16 scatter)
__device__ __forceinline__ void gload16(const void* g, void* l) {
  __builtin_amdgcn_global_load_lds(
      (const __attribute__((address_space(1))) void*)g,
      (__attribute__((address_space(3))) void*)l, 16, 0, 0);
}

// chunked-bijective XCD swizzle (m204): dispatch id b -> linear tile id such
// that blocks resident on one XCD (b%8 round-robin) cover a contiguous chunk
// of tiles -> per-XCD L2 working set stays small.
__device__ __forceinline__ int xcd_chunk_lin(int b, int nwg) {
  const int c = b & 7, s = b >> 3;
  const int q = nwg >> 3, r = nwg & 7;
  const int off = (c < r) ? c * (q + 1) : r * (q + 1) + (c - r) * q;
  return off + s;
}

// ---------------- zero workspace region ----------------
__global__ __launch_bounds__(256) void zero_kernel(float4* __restrict__ p,
                                                   int n4) {
  const int i = blockIdx.x * 256 + threadIdx.x;
  if (i < n4) p[i] = make_float4(0.f, 0.f, 0.f, 0.f);
}

// ---------------- cast kernels ----------------
// pooled-gather x -> fp16 A matrix [12544, 384]
__global__ __launch_bounds__(256) void pool_cast_kernel(
    const float* __restrict__ x, f16* __restrict__ xp) {
  const int i = (blockIdx.x * 256 + threadIdx.x) * 4;  // < 12544*384, %4==0
  const int row = i / CDIM, col = i % CDIM;
  const int b = row / NQ, qi = row % NQ;
  const int hi = qi / 28, wi = qi % 28;
  const float4 v =
      *(const float4*)(x + ((size_t)(b * NPIX + hi * 112 + wi * 2)) * CDIM + col);
  f16x4 h;
  h.x = (f16)v.x; h.y = (f16)v.y; h.z = (f16)v.z; h.w = (f16)v.w;
  *(f16x4*)(xp + i) = h;
}

__global__ __launch_bounds__(256) void w_cast_kernel(
    const float* __restrict__ src, f16* __restrict__ dst, int n) {
  const int i = (blockIdx.x * 256 + threadIdx.x) * 4;
  if (i >= n) return;
  const float4 v = *(const float4*)(src + i);
  f16x4 h;
  h.x = (f16)v.x; h.y = (f16)v.y; h.z = (f16)v.z; h.w = (f16)v.w;
  *(f16x4*)(dst + i) = h;
}

// ---------------- shared MFMA tile GEMM body (LDS double-buffered) ----------------
// C(128x128 tile at m0,n0) = A[M,K] @ B[N,K]^T, fp16 in, fp32 acc.
// One barrier per K-step; next tile's global_load_lds issued into the other
// buffer right after the barrier so HBM/L2 latency hides under ds_read+MFMA.
__device__ __forceinline__ void mfma_tile_gemm_db(
    const f16* __restrict__ A, const f16* __restrict__ B, int m0, int n0,
    int K, f32x4 (&acc)[4][4], f16* As, f16* Bs) {
  const int t = threadIdx.x;
  const int lane = t & 63, w = t >> 6;
  const int wm = w >> 1, wn = w & 1;
  const int l15 = lane & 15, l4 = lane >> 4;
  const int rowS = t >> 2;
  const int kb = (t & 3) * 16;
  char* AsB = (char*)As;
  char* BsB = (char*)Bs;
  const char* Ag = (const char*)A + ((size_t)(m0 + rowS) * K) * 2 + kb;
  const char* Bg = (const char*)B + ((size_t)(n0 + rowS) * K) * 2 + kb;
  const size_t row64 = (size_t)64 * K * 2;

  // prologue: stage k0=0 into buffer 0
  gload16(Ag, AsB + t * 16);
  gload16(Ag + row64, AsB + 4096 + t * 16);
  gload16(Bg, BsB + t * 16);
  gload16(Bg + row64, BsB + 4096 + t * 16);

  int cur = 0;
  for (int k0 = 0; k0 < K; k0 += 32) {
    __syncthreads();  // buf `cur` staged (vmcnt drain) + other buf free
    if (k0 + 32 < K) {
      const int nb_ = cur ^ 1;
      const char* Ag2 = Ag + (size_t)(k0 + 32) * 2;
      const char* Bg2 = Bg + (size_t)(k0 + 32) * 2;
      gload16(Ag2, AsB + nb_ * 8192 + t * 16);
      gload16(Ag2 + row64, AsB + nb_ * 8192 + 4096 + t * 16);
      gload16(Bg2, BsB + nb_ * 8192 + t * 16);
      gload16(Bg2 + row64, BsB + nb_ * 8192 + 4096 + t * 16);
    }
    const char* Ab = AsB + cur * 8192;
    const char* Bb = BsB + cur * 8192;
    f16x8 af[4], bf[4];
#pragma unroll
    for (int i = 0; i < 4; ++i)
      af[i] = *(const f16x8*)(Ab + ((wm * 64 + i * 16 + l15) * 64 + l4 * 16));
#pragma unroll
    for (int j = 0; j < 4; ++j)
      bf[j] = *(const f16x8*)(Bb + ((wn * 64 + j * 16 + l15) * 64 + l4 * 16));
#pragma unroll
    for (int i = 0; i < 4; ++i)
#pragma unroll
      for (int j = 0; j < 4; ++j)
        acc[i][j] =
            __builtin_amdgcn_mfma_f32_16x16x32_f16(af[i], bf[j], acc[i][j], 0, 0, 0);
    cur ^= 1;
  }
}

// ---------------- Kernel A: QKV GEMM (fp16 MFMA) ----------------
// 1D grid 882 = 98 m-tiles x 9 n-tiles, XCD-chunk swizzled. Each n-tile lies
// in exactly one of q/k/v (1152 = 3*384, 384 = 3*128).
// Epilogue transposes the 128x128 result through LDS so all global stores are
// 16B vectors: q/k as [bh][tok][48] rows (96B runs), v^T as [bh][d][832]
// qi-contiguous runs. This removes the 2-byte scatter (64 lines/inst) that
// pinned this kernel at ~53us across three different K-loop structures.
__global__ __launch_bounds__(256) void qkv_mfma_kernel(
    const f16* __restrict__ xp, const f16* __restrict__ wh,
    const float* __restrict__ qkv_b, f16* __restrict__ qh,
    f16* __restrict__ kh, f16* __restrict__ vt) {
  __shared__ union SU {
    struct { f16 As[2 * 128 * 32]; f16 Bs[2 * 128 * 32]; } s;  // 32 KB
    f16 Tr[128][136];                                          // 34 KB
  } u;
  const int lin = xcd_chunk_lin(blockIdx.x, 882);
  const int m0 = (lin / 9) * 128, n0 = (lin % 9) * 128;
  f32x4 acc[4][4] = {};
  mfma_tile_gemm_db(xp, wh, m0, n0, CDIM, acc, u.s.As, u.s.Bs);

  const int t = threadIdx.x, lane = t & 63, w = t >> 6;
  const int wm = w >> 1, wn = w & 1;
  const int l15 = lane & 15, l4 = lane >> 4;
  const int sec = n0 / CDIM;  // 0=q, 1=k, 2=v (block-uniform)
  const float scl = (sec == 0) ? QK_SCALE : 1.f;

  __syncthreads();  // all LDS reads of As/Bs complete before aliasing as Tr

  if (sec < 2) {
    // Tr[qi_local][f_local]
#pragma unroll
    for (int j = 0; j < 4; ++j) {
      const int fl_ = wn * 64 + j * 16 + l15;
      const float bias = qkv_b[n0 + fl_];
#pragma unroll
      for (int i = 0; i < 4; ++i)
#pragma unroll
        for (int r = 0; r < 4; ++r)
          u.Tr[wm * 64 + i * 16 + l4 * 4 + r][fl_] =
              (f16)((acc[i][j][r] + bias) * scl);
    }
  } else {
    // Tr[f_local][qi_local]
#pragma unroll
    for (int j = 0; j < 4; ++j) {
      const int fl_ = wn * 64 + j * 16 + l15;
      const float bias = qkv_b[n0 + fl_];
#pragma unroll
      for (int i = 0; i < 4; ++i)
#pragma unroll
        for (int r = 0; r < 4; ++r)
          u.Tr[fl_][wm * 64 + i * 16 + l4 * 4 + r] = (f16)(acc[i][j][r] + bias);
    }
  }
  __syncthreads();

  // read back 16B units, store wide. 2048 units, 8 per thread; 16-lane groups
  // cover one Tr row -> global runs of 96B (q/k) / 128B (vt). 8-unit spans
  // never straddle head (48%8==0) or batch (784%8==0) boundaries.
#pragma unroll
  for (int c = 0; c < 8; ++c) {
    const int v = c * 256 + t;
    const int rr = v >> 4, u16 = v & 15;
    if (sec < 2) {
      const int qi_l = rr, f_l = u16 * 8;
      const int fr = n0 + f_l - sec * CDIM;
      const int hh = fr / HD, d = fr - hh * HD;
      const int mm = m0 + qi_l, b = mm / NQ, tok = mm - b * NQ;
      f16* dst = (sec == 0 ? qh : kh) +
                 ((size_t)(b * NHEADS + hh) * NQ + tok) * HD + d;
      *(f16x8*)dst = *(const f16x8*)&u.Tr[qi_l][f_l];
    } else {
      const int f_l = rr, qi0 = u16 * 8;
      const int fr = n0 + f_l - 2 * CDIM;
      const int hh = fr / HD, d = fr - hh * HD;
      const int mm = m0 + qi0, b = mm / NQ, tok = mm - b * NQ;
      f16* dst = vt + ((size_t)(b * NHEADS + hh) * HD + d) * NQPAD + tok;
      *(f16x8*)dst = *(const f16x8*)&u.Tr[f_l][qi0];
    }
  }
}

// ---------------- Kernel B: fused flash attention (no-max softmax) ----------------
// 128 q-rows per block. q/k are stored packed [bh][tok][48]; QK^T runs
// k=0..63 with LDS-zeroed pad cols 48..63 (two chained 16x16x32 MFMAs).
// Q fragments hoisted to regs so Qs LDS is recycled as the Ps buffer; Ps
// stride 68 keeps the scalar P stores spread; K/V staging is reg-prefetched.
__global__ __launch_bounds__(256) void flash_kernel(
    const f16* __restrict__ qh, const f16* __restrict__ kh,
    const f16* __restrict__ vt, f16* __restrict__ o16) {
  __shared__ f16 PQ[128 * 72];     // 18432 B: Qs[128][72]; recycled as Ps[4][32][68]
  __shared__ f16 Ks[64][72];       // 9216 B
  __shared__ f16 Vts[48][72];      // 6912 B

  f16 (*Qs)[72] = (f16(*)[72])PQ;
  f16 (*Ps)[32][68] = (f16(*)[32][68])PQ;

  const int t = threadIdx.x;
  const int lane = t & 63, w = t >> 6;
  const int quad = lane >> 4, l15 = lane & 15;
  const int q0 = blockIdx.x * 128;
  const int bh = blockIdx.y;

  const f16* qg = qh + (size_t)bh * NQ * HD;
  const f16* kg = kh + (size_t)bh * NQ * HD;
  const f16* vg = vt + (size_t)bh * HD * NQPAD;

  // ---- zero k-pad cols 48..63 of Qs (256 units) and Ks (128 units) ----
  {
    const f16x8 z8 = {};
    *(f16x8*)&Qs[t >> 1][48 + (t & 1) * 8] = z8;
    if (t < 128) *(f16x8*)&Ks[t >> 1][48 + (t & 1) * 8] = z8;
  }

  // ---- stage Q tile: 128 rows x 48 cols (6 segs of 16B) ----
#pragma unroll
  for (int c = 0; c < 3; ++c) {
    const int u = t + c * 256;  // < 768
    const int row = u / 6, seg = u % 6;
    const int gr = min(q0 + row, NQ - 1);
    *(f16x8*)&Qs[row][seg * 8] =
        *(const f16x8*)(qg + (size_t)gr * HD + seg * 8);
  }
  __syncthreads();

  // ---- hoist Q fragments (Qs LDS is recycled as Ps after this) ----
  f16x8 qf0[2], qf1[2];
#pragma unroll
  for (int qa = 0; qa < 2; ++qa) {
    const int row = w * 32 + qa * 16 + l15;
    qf0[qa] = *(const f16x8*)&Qs[row][quad * 8];
    qf1[qa] = *(const f16x8*)&Qs[row][32 + quad * 8];
  }

  // ---- staging plan: 768 16B-units per K/V tile = 3 per thread ----
  const f16* gp[3];
  f16* lp[3];
  int step[3];
#pragma unroll
  for (int c = 0; c < 3; ++c) {
    const int u = t + c * 256;
    if (u < 384) {  // K: 64 rows x 6 segs (cols 0..47)
      const int row = u / 6, seg = u % 6;
      gp[c] = kg + (size_t)row * HD + seg * 8;
      lp[c] = &Ks[row][seg * 8];
      step[c] = 64 * HD;
    } else {        // V^T: 48 rows x 8 segs
      const int uv = u - 384;
      const int row = uv >> 3, seg = uv & 7;
      gp[c] = vg + (size_t)row * NQPAD + seg * 8;
      lp[c] = &Vts[row][seg * 8];
      step[c] = 64;
    }
  }

  // prologue: issue tile 0 loads
  f16x8 rg[3];
#pragma unroll
  for (int c = 0; c < 3; ++c) {
    rg[c] = *(const f16x8*)gp[c];
    gp[c] += step[c];
  }

  f32x4 accO[2][3] = {};
  float l_[2][4] = {};

  for (int kt = 0; kt < 13; ++kt) {
    // commit staged tile kt to LDS (cols 0..47 only; pads stay zero)
#pragma unroll
    for (int c = 0; c < 3; ++c) *(f16x8*)lp[c] = rg[c];
    __syncthreads();
    // issue tile kt+1 loads; HBM latency hides under compute below
    if (kt < 12) {
#pragma unroll
      for (int c = 0; c < 3; ++c) {
        rg[c] = *(const f16x8*)gp[c];
        gp[c] += step[c];
      }
    }

    // ---- QK^T (k=0..63, pad zeros) fused with exp2 + row-sum + P store ----
    const bool last = (kt == 12);
#pragma unroll
    for (int j = 0; j < 4; ++j) {
      const f16x8 b0 = *(const f16x8*)&Ks[j * 16 + l15][quad * 8];
      const f16x8 b1 = *(const f16x8*)&Ks[j * 16 + l15][32 + quad * 8];
      f32x4 z0 = {}, z1 = {};
      z0 = __builtin_amdgcn_mfma_f32_16x16x32_f16(qf0[0], b0, z0, 0, 0, 0);
      const f32x4 sj0 = __builtin_amdgcn_mfma_f32_16x16x32_f16(qf1[0], b1, z0, 0, 0, 0);
      z1 = __builtin_amdgcn_mfma_f32_16x16x32_f16(qf0[1], b0, z1, 0, 0, 0);
      const f32x4 sj1 = __builtin_amdgcn_mfma_f32_16x16x32_f16(qf1[1], b1, z1, 0, 0, 0);
      const bool msk = last && (j >= 1);  // keys >= 784
#pragma unroll
      for (int r = 0; r < 4; ++r) {
        const float p0 = msk ? 0.f : fast_exp2(sj0[r]);
        const float p1 = msk ? 0.f : fast_exp2(sj1[r]);
        l_[0][r] += p0;
        l_[1][r] += p1;
        Ps[w][quad * 4 + r][j * 16 + l15] = (f16)p0;
        Ps[w][16 + quad * 4 + r][j * 16 + l15] = (f16)p1;
      }
    }

    // ---- P fragments (8B-aligned b64 pairs; stride 68 spreads banks) ----
    f16x8 ap0[2], ap1[2];
#pragma unroll
    for (int qa = 0; qa < 2; ++qa) {
      const int row = qa * 16 + l15;
      const f16x4 a0 = *(const f16x4*)&Ps[w][row][quad * 8];
      const f16x4 a1 = *(const f16x4*)&Ps[w][row][quad * 8 + 4];
      const f16x4 a2 = *(const f16x4*)&Ps[w][row][32 + quad * 8];
      const f16x4 a3 = *(const f16x4*)&Ps[w][row][32 + quad * 8 + 4];
      ap0[qa] = __builtin_shufflevector(a0, a1, 0, 1, 2, 3, 4, 5, 6, 7);
      ap1[qa] = __builtin_shufflevector(a2, a3, 0, 1, 2, 3, 4, 5, 6, 7);
    }

    // ---- PV ----
#pragma unroll
    for (int jn = 0; jn < 3; ++jn) {
      const f16x8 v0 = *(const f16x8*)&Vts[jn * 16 + l15][quad * 8];
      const f16x8 v1 = *(const f16x8*)&Vts[jn * 16 + l15][32 + quad * 8];
#pragma unroll
      for (int qa = 0; qa < 2; ++qa) {
        accO[qa][jn] =
            __builtin_amdgcn_mfma_f32_16x16x32_f16(ap0[qa], v0, accO[qa][jn], 0, 0, 0);
        accO[qa][jn] =
            __builtin_amdgcn_mfma_f32_16x16x32_f16(ap1[qa], v1, accO[qa][jn], 0, 0, 0);
      }
    }
    __syncthreads();
  }

  // ---- normalize + store ----
  const int b = bh >> 3, hh = bh & 7;
#pragma unroll
  for (int qa = 0; qa < 2; ++qa) {
#pragma unroll
    for (int r = 0; r < 4; ++r) {
      float rs = l_[qa][r];
      rs += __shfl_xor(rs, 1);
      rs += __shfl_xor(rs, 2);
      rs += __shfl_xor(rs, 4);
      rs += __shfl_xor(rs, 8);
      const int qrow = q0 + w * 32 + qa * 16 + quad * 4 + r;
      if (qrow < NQ) {
        const float inv = 1.f / rs;
#pragma unroll
        for (int jn = 0; jn < 3; ++jn)
          o16[((size_t)(b * NQ + qrow)) * CDIM + hh * HD + jn * 16 + l15] =
              (f16)(accO[qa][jn][r] * inv);
      }
    }
  }
}

// ---------------- Kernel C1: per-row LN stats for the 4 upsample phases ----------------
// u_pq = o * lp_w[:,pq] + lp_b; stats[m][pq] = (mu, rstd). One wave per row.
__global__ __launch_bounds__(256) void stats_kernel(
    const f16* __restrict__ o16, const float* __restrict__ lp_w,
    const float* __restrict__ lp_b, float* __restrict__ stats) {
  const int m = blockIdx.x * 4 + (threadIdx.x >> 6);
  const int lane = threadIdx.x & 63;
  float s[4] = {}, ss[4] = {};
#pragma unroll
  for (int i = 0; i < 6; ++i) {
    const int c = lane + i * 64;
    const float ov = (float)o16[(size_t)m * CDIM + c];
    const float4 w4 = *(const float4*)(lp_w + c * 4);
    const float bb = lp_b[c];
    const float u0 = ov * w4.x + bb;
    const float u1 = ov * w4.y + bb;
    const float u2 = ov * w4.z + bb;
    const float u3 = ov * w4.w + bb;
    s[0] += u0; ss[0] += u0 * u0;
    s[1] += u1; ss[1] += u1 * u1;
    s[2] += u2; ss[2] += u2 * u2;
    s[3] += u3; ss[3] += u3 * u3;
  }
#pragma unroll
  for (int pq = 0; pq < 4; ++pq) {
    s[pq] = waveSum(s[pq]);
    ss[pq] = waveSum(ss[pq]);
  }
  if (lane < 4) {
    const float mu = s[lane] * (1.f / CDIM);
    const float var = ss[lane] * (1.f / CDIM) - mu * mu;
    stats[m * 8 + lane * 2] = mu;
    stats[m * 8 + lane * 2 + 1] = rsqrtf(var + LN_EPS);
  }
}

// ---------------- Kernel C2: W_pq = proj_w * (lp_w[:,pq]*ln_w) * WSCALE -> f16 ----------------
// Layout [f=pq*384+j][c].
__global__ __launch_bounds__(256) void wprep_kernel(
    const float* __restrict__ pw, const float* __restrict__ lpw,
    const float* __restrict__ lnw, f16* __restrict__ wq) {
  const int i4 = (blockIdx.x * 256 + threadIdx.x) * 4;  // < 1536*384
  const int f = i4 / CDIM, c = i4 % CDIM;
  const int pq = f / CDIM, j = f % CDIM;
  const float4 wv = *(const float4*)(pw + (size_t)j * CDIM + c);
  const float4 ln = *(const float4*)(lnw + c);
  f16x4 h;
  h.x = (f16)(wv.x * lpw[(c + 0) * 4 + pq] * ln.x * WSCALE);
  h.y = (f16)(wv.y * lpw[(c + 1) * 4 + pq] * ln.y * WSCALE);
  h.z = (f16)(wv.z * lpw[(c + 2) * 4 + pq] * ln.z * WSCALE);
  h.w = (f16)(wv.w * lpw[(c + 3) * 4 + pq] * ln.w * WSCALE);
  *(f16x4*)(wq + i4) = h;
}

// ---------------- Kernel C3: constant vectors ----------------
// c1[j]=sum_c lp_b*ln_w*W[j][c]; c2[j]=sum_c ln_w*W[j][c]; c3[j]=sum_c ln_b*W[j][c]+pb[j]
__global__ __launch_bounds__(64) void cvec_kernel(
    const float* __restrict__ pw, const float* __restrict__ lp_b,
    const float* __restrict__ ln_w, const float* __restrict__ ln_b,
    const float* __restrict__ pb, float* __restrict__ cvec) {
  const int j = blockIdx.x;
  const int lane = threadIdx.x;
  float a1 = 0.f, a2 = 0.f, a3 = 0.f;
#pragma unroll
  for (int i = 0; i < 6; ++i) {
    const int c = lane + i * 64;
    const float wv = pw[(size_t)j * CDIM + c];
    a1 += lp_b[c] * ln_w[c] * wv;
    a2 += ln_w[c] * wv;
    a3 += ln_b[c] * wv;
  }
  a1 = waveSum(a1);
  a2 = waveSum(a2);
  a3 = waveSum(a3);
  if (lane == 0) {
    cvec[j] = a1;
    cvec[CDIM + j] = a2;
    cvec[2 * CDIM + j] = a3 + pb[j];
  }
}

// ---------------- Kernel D: fused upsample+LN+proj GEMM ----------------
// G = o16 @ wq^T  (M=12544, N=1536, K=384); out row (m,pq) -> pixel scatter.
// 1D grid 1176 = 98 m-tiles x 12 n-tiles, XCD-chunk swizzled; each block's
// 128-col range lies in exactly one pq (384=3*128). out stores are 64B
// f32 runs (acceptable granule).
__global__ __launch_bounds__(256) void projfused_kernel(
    const f16* __restrict__ o16, const f16* __restrict__ wq,
    const float* __restrict__ stats, const float* __restrict__ cvec,
    float* __restrict__ out) {
  __shared__ f16 As[2 * 128 * 32];
  __shared__ f16 Bs[2 * 128 * 32];
  const int lin = xcd_chunk_lin(blockIdx.x, 1176);
  const int m0 = (lin / 12) * 128, n0 = (lin % 12) * 128;
  f32x4 acc[4][4] = {};
  mfma_tile_gemm_db(o16, wq, m0, n0, CDIM, acc, As, Bs);

  const int t = threadIdx.x, lane = t & 63, w = t >> 6;
  const int wm = w >> 1, wn = w & 1;
  const int l15 = lane & 15, l4 = lane >> 4;
  const int pq = n0 / CDIM;  // uniform per block
  const int p = pq >> 1, q = pq & 1;
  const int c0 = n0 - pq * CDIM;

  float C1[4], C2[4], C3[4];
#pragma unroll
  for (int j = 0; j < 4; ++j) {
    const int col = c0 + wn * 64 + j * 16 + l15;
    C1[j] = cvec[col];
    C2[j] = cvec[CDIM + col];
    C3[j] = cvec[2 * CDIM + col];
  }

#pragma unroll
  for (int i = 0; i < 4; ++i) {
#pragma unroll
    for (int r = 0; r < 4; ++r) {
      const int m = m0 + wm * 64 + i * 16 + l4 * 4 + r;
      const int b = m / NQ, n = m % NQ;
      const int hi2 = n / 28, wi2 = n % 28;
      const float mu = stats[m * 8 + pq * 2];
      const float rstd = stats[m * 8 + pq * 2 + 1];
      const int pix = (hi2 * 2 + p) * HWD + (wi2 * 2 + q);
      float* orow = out + ((size_t)(b * NPIX + pix)) * CDIM;
#pragma unroll
      for (int j = 0; j < 4; ++j) {
        const int col = c0 + wn * 64 + j * 16 + l15;
        orow[col] = rstd * (acc[i][j][r] * WUNSCALE + C1[j] - mu * C2[j]) + C3[j];
      }
    }
  }
}

extern "C" void kernel_launch(void* const* d_in, const int* in_sizes, int n_in,
                              void* d_out, int out_size, void* d_ws,
                              size_t ws_size, hipStream_t stream) {
  const float* x      = (const float*)d_in[0];
  const float* qkv_w  = (const float*)d_in[1];
  const float* qkv_b  = (const float*)d_in[2];
  const float* proj_w = (const float*)d_in[3];
  const float* proj_b = (const float*)d_in[4];
  const float* lp_w   = (const float*)d_in[5];
  const float* lp_b   = (const float*)d_in[6];
  const float* ln_w   = (const float*)d_in[7];
  const float* ln_b   = (const float*)d_in[8];
  float* out = (float*)d_out;

  // workspace layout (float offsets), total ~13.7M floats = 55 MB
  float* ws = (float*)d_ws;
  f16* o16 = (f16*)ws;                        // [12544][384]   4,816,896 f16 (2,408,448 fl)
  float* zreg = ws + 2408448;                 // region: qh,kh,vt (only vt needs zeroing)
  f16* qh = (f16*)zreg;                       // [128][784][48] 4,816,896 f16
  f16* kh = qh + (size_t)128 * NQ * HD;       // [128][784][48] 4,816,896 f16
  f16* vt = kh + (size_t)128 * NQ * HD;       // [128][48][832] 5,111,808 f16
  float* rest = zreg + 7372800;               // end of q/k/v region
  f16* xp = (f16*)rest;                       // [12544][384]   4,816,896 f16
  f16* qkv_wh = xp + (size_t)12544 * CDIM;    // [1152][384]      442,368 f16
  float* rest2 = rest + 2408448 + 221184;
  f16* wq = (f16*)rest2;                      // [1536][384]    2,359,296 f16 (1,179,648 fl)
  float* cvec = rest2 + 1179648;              // [3][384]           1,152 fl
  float* stats = cvec + 1152;                 // [12544][4][2]    100,352 fl

  // 0) zero v^T pad tokens (q/k have no pads anymore)
  zero_kernel<<<dim3(2496), 256, 0, stream>>>((float4*)(zreg + 4816896), 638976);

  // 1) casts + pooled qkv (fp16 MFMA)
  pool_cast_kernel<<<dim3(4704), 256, 0, stream>>>(x, xp);
  w_cast_kernel<<<dim3(432), 256, 0, stream>>>(qkv_w, qkv_wh, 1152 * CDIM);
  qkv_mfma_kernel<<<dim3(882), 256, 0, stream>>>(xp, qkv_wh, qkv_b, qh, kh, vt);

  // 2) fused flash attention -> fp16 o (128 q-rows/block)
  flash_kernel<<<dim3(7, 128), 256, 0, stream>>>(qh, kh, vt, o16);

  // 3) LN stats + folded weights + constant vectors
  stats_kernel<<<dim3(3136), 256, 0, stream>>>(o16, lp_w, lp_b, stats);
  wprep_kernel<<<dim3(576), 256, 0, stream>>>(proj_w, lp_w, ln_w, wq);
  cvec_kernel<<<dim3(384), 64, 0, stream>>>(proj_w, lp_b, ln_w, ln_b, proj_b,
                                            cvec);

  // 4) fused upsample+LN+proj GEMM
  projfused_kernel<<<dim3(1176), 256, 0, stream>>>(o16, wq, stats, cvec, out);
}

// Round 7
// 242.775 us; speedup vs baseline: 1.1887x; 1.0489x over previous
//
#include <hip/hip_runtime.h>
#include <math.h>

#define CDIM 384
#define NHEADS 8
#define HD 48
#define NQ 784      // 28*28 pooled tokens
#define NQPAD 832   // 13*64, zero-padded k/n extent for V^T
#define NB 16
#define HWD 56
#define NPIX 3136   // 56*56
// 48^-0.5 * log2(e): scores land in exp2 domain, softmax uses raw v_exp_f32
#define QK_SCALE (0.14433756729740643f * 1.4426950408889634f)
#define LN_EPS 1e-5f
#define WSCALE 16.0f     // fold into W_pq to stay clear of f16 denormals
#define WUNSCALE 0.0625f

typedef _Float16 f16;
typedef _Float16 f16x4 __attribute__((ext_vector_type(4)));
typedef _Float16 f16x8 __attribute__((ext_vector_type(8)));
typedef float f32x4 __attribute__((ext_vector_type(4)));

// ---------------- wave/block reduction helpers ----------------
__device__ __forceinline__ float waveSum(float v) {
#pragma unroll
  for (int o = 32; o > 0; o >>= 1) v += __shfl_xor(v, o);
  return v;
}

__device__ __forceinline__ float fast_exp2(float x) {
#if __has_builtin(__builtin_amdgcn_exp2f)
  return __builtin_amdgcn_exp2f(x);
#else
  return __expf(x * 0.6931471805599453f);
#endif
}

// async global->LDS 16B copy (wave-uniform lds base + lane*16 scatter)
__device__ __forceinline__ void gload16(const void* g, void* l) {
  __builtin_amdgcn_global_load_lds(
      (const __attribute__((address_space(1))) void*)g,
      (__attribute__((address_space(3))) void*)l, 16, 0, 0);
}

// chunked-bijective XCD swizzle (m204): dispatch id b -> linear tile id such
// that blocks resident on one XCD (b%8 round-robin) cover a contiguous chunk
// of tiles -> per-XCD L2 working set stays small.
__device__ __forceinline__ int xcd_chunk_lin(int b, int nwg) {
  const int c = b & 7, s = b >> 3;
  const int q = nwg >> 3, r = nwg & 7;
  const int off = (c < r) ? c * (q + 1) : r * (q + 1) + (c - r) * q;
  return off + s;
}

// ---------------- Kernel P: fused prep (launch-count reduction) ----------------
// Branch ladder over independent jobs, all input-only:
//  [0,4704)      pool_cast: pooled-gather x -> fp16 A [12544,384]
//  [4704,5136)   w_cast: qkv_w -> f16
//  [5136,5280)   zero vt pad tokens (784..831 per [bh][d] row; 36864 float4)
//  [5280,5856)   wprep: W_pq = proj_w * lp_w[:,pq] * ln_w * WSCALE -> f16
//  [5856,5952)   cvec: 3 constant vectors (4 j-rows per block, 1 per wave)
__global__ __launch_bounds__(256) void prep_kernel(
    const float* __restrict__ x, f16* __restrict__ xp,
    const float* __restrict__ qkv_w, f16* __restrict__ qkv_wh,
    f16* __restrict__ vt, const float* __restrict__ pw,
    const float* __restrict__ lpw, const float* __restrict__ lnw,
    const float* __restrict__ lp_b, const float* __restrict__ ln_b,
    const float* __restrict__ pb, f16* __restrict__ wq,
    float* __restrict__ cvec) {
  const int blk = blockIdx.x, t = threadIdx.x;
  if (blk < 4704) {
    const int i = (blk * 256 + t) * 4;
    const int row = i / CDIM, col = i % CDIM;
    const int b = row / NQ, qi = row % NQ;
    const int hi = qi / 28, wi = qi % 28;
    const float4 v =
        *(const float4*)(x + ((size_t)(b * NPIX + hi * 112 + wi * 2)) * CDIM + col);
    f16x4 h;
    h.x = (f16)v.x; h.y = (f16)v.y; h.z = (f16)v.z; h.w = (f16)v.w;
    *(f16x4*)(xp + i) = h;
  } else if (blk < 5136) {
    const int i = ((blk - 4704) * 256 + t) * 4;  // < 1152*384
    const float4 v = *(const float4*)(qkv_w + i);
    f16x4 h;
    h.x = (f16)v.x; h.y = (f16)v.y; h.z = (f16)v.z; h.w = (f16)v.w;
    *(f16x4*)(qkv_wh + i) = h;
  } else if (blk < 5280) {
    const int idx = (blk - 5136) * 256 + t;  // < 36864
    const int row = idx / 6, off = idx % 6;  // row < 6144 = 128*48
    float4* p = (float4*)vt + (size_t)row * 104 + 98 + off;  // 832*2B=104 f4
    *p = make_float4(0.f, 0.f, 0.f, 0.f);
  } else if (blk < 5856) {
    const int i4 = ((blk - 5280) * 256 + t) * 4;  // < 1536*384
    const int f = i4 / CDIM, c = i4 % CDIM;
    const int pq = f / CDIM, j = f % CDIM;
    const float4 wv = *(const float4*)(pw + (size_t)j * CDIM + c);
    const float4 ln = *(const float4*)(lnw + c);
    f16x4 h;
    h.x = (f16)(wv.x * lpw[(c + 0) * 4 + pq] * ln.x * WSCALE);
    h.y = (f16)(wv.y * lpw[(c + 1) * 4 + pq] * ln.y * WSCALE);
    h.z = (f16)(wv.z * lpw[(c + 2) * 4 + pq] * ln.z * WSCALE);
    h.w = (f16)(wv.w * lpw[(c + 3) * 4 + pq] * ln.w * WSCALE);
    *(f16x4*)(wq + i4) = h;
  } else {
    const int j = (blk - 5856) * 4 + (t >> 6);  // < 384
    const int lane = t & 63;
    float a1 = 0.f, a2 = 0.f, a3 = 0.f;
#pragma unroll
    for (int i = 0; i < 6; ++i) {
      const int c = lane + i * 64;
      const float wv = pw[(size_t)j * CDIM + c];
      a1 += lp_b[c] * lnw[c] * wv;
      a2 += lnw[c] * wv;
      a3 += ln_b[c] * wv;
    }
    a1 = waveSum(a1);
    a2 = waveSum(a2);
    a3 = waveSum(a3);
    if (lane == 0) {
      cvec[j] = a1;
      cvec[CDIM + j] = a2;
      cvec[2 * CDIM + j] = a3 + pb[j];
    }
  }
}

// ---------------- shared MFMA tile GEMM body (LDS double-buffered) ----------------
// C(128x128 tile at m0,n0) = A[M,K] @ B[N,K]^T, fp16 in, fp32 acc.
// One barrier per K-step; next tile's global_load_lds issued into the other
// buffer right after the barrier so HBM/L2 latency hides under ds_read+MFMA.
__device__ __forceinline__ void mfma_tile_gemm_db(
    const f16* __restrict__ A, const f16* __restrict__ B, int m0, int n0,
    int K, f32x4 (&acc)[4][4], f16* As, f16* Bs) {
  const int t = threadIdx.x;
  const int lane = t & 63, w = t >> 6;
  const int wm = w >> 1, wn = w & 1;
  const int l15 = lane & 15, l4 = lane >> 4;
  const int rowS = t >> 2;
  const int kb = (t & 3) * 16;
  char* AsB = (char*)As;
  char* BsB = (char*)Bs;
  const char* Ag = (const char*)A + ((size_t)(m0 + rowS) * K) * 2 + kb;
  const char* Bg = (const char*)B + ((size_t)(n0 + rowS) * K) * 2 + kb;
  const size_t row64 = (size_t)64 * K * 2;

  // prologue: stage k0=0 into buffer 0
  gload16(Ag, AsB + t * 16);
  gload16(Ag + row64, AsB + 4096 + t * 16);
  gload16(Bg, BsB + t * 16);
  gload16(Bg + row64, BsB + 4096 + t * 16);

  int cur = 0;
  for (int k0 = 0; k0 < K; k0 += 32) {
    __syncthreads();  // buf `cur` staged (vmcnt drain) + other buf free
    if (k0 + 32 < K) {
      const int nb_ = cur ^ 1;
      const char* Ag2 = Ag + (size_t)(k0 + 32) * 2;
      const char* Bg2 = Bg + (size_t)(k0 + 32) * 2;
      gload16(Ag2, AsB + nb_ * 8192 + t * 16);
      gload16(Ag2 + row64, AsB + nb_ * 8192 + 4096 + t * 16);
      gload16(Bg2, BsB + nb_ * 8192 + t * 16);
      gload16(Bg2 + row64, BsB + nb_ * 8192 + 4096 + t * 16);
    }
    const char* Ab = AsB + cur * 8192;
    const char* Bb = BsB + cur * 8192;
    f16x8 af[4], bf[4];
#pragma unroll
    for (int i = 0; i < 4; ++i)
      af[i] = *(const f16x8*)(Ab + ((wm * 64 + i * 16 + l15) * 64 + l4 * 16));
#pragma unroll
    for (int j = 0; j < 4; ++j)
      bf[j] = *(const f16x8*)(Bb + ((wn * 64 + j * 16 + l15) * 64 + l4 * 16));
#pragma unroll
    for (int i = 0; i < 4; ++i)
#pragma unroll
      for (int j = 0; j < 4; ++j)
        acc[i][j] =
            __builtin_amdgcn_mfma_f32_16x16x32_f16(af[i], bf[j], acc[i][j], 0, 0, 0);
    cur ^= 1;
  }
}

// ---------------- Kernel A: QKV GEMM (fp16 MFMA) ----------------
// 1D grid 882 = 98 m-tiles x 9 n-tiles, XCD-chunk swizzled. Each n-tile lies
// in exactly one of q/k/v. Epilogue transposes the 128x128 result through LDS
// so all global stores are 16B vectors (removes the 2-byte scatter that
// pinned this kernel at ~53us across three K-loop structures).
__global__ __launch_bounds__(256) void qkv_mfma_kernel(
    const f16* __restrict__ xp, const f16* __restrict__ wh,
    const float* __restrict__ qkv_b, f16* __restrict__ qh,
    f16* __restrict__ kh, f16* __restrict__ vt) {
  __shared__ union SU {
    struct { f16 As[2 * 128 * 32]; f16 Bs[2 * 128 * 32]; } s;  // 32 KB
    f16 Tr[128][136];                                          // 34 KB
  } u;
  const int lin = xcd_chunk_lin(blockIdx.x, 882);
  const int m0 = (lin / 9) * 128, n0 = (lin % 9) * 128;
  f32x4 acc[4][4] = {};
  mfma_tile_gemm_db(xp, wh, m0, n0, CDIM, acc, u.s.As, u.s.Bs);

  const int t = threadIdx.x, lane = t & 63, w = t >> 6;
  const int wm = w >> 1, wn = w & 1;
  const int l15 = lane & 15, l4 = lane >> 4;
  const int sec = n0 / CDIM;  // 0=q, 1=k, 2=v (block-uniform)
  const float scl = (sec == 0) ? QK_SCALE : 1.f;

  __syncthreads();  // all LDS reads of As/Bs complete before aliasing as Tr

  if (sec < 2) {
    // Tr[qi_local][f_local]
#pragma unroll
    for (int j = 0; j < 4; ++j) {
      const int fl_ = wn * 64 + j * 16 + l15;
      const float bias = qkv_b[n0 + fl_];
#pragma unroll
      for (int i = 0; i < 4; ++i)
#pragma unroll
        for (int r = 0; r < 4; ++r)
          u.Tr[wm * 64 + i * 16 + l4 * 4 + r][fl_] =
              (f16)((acc[i][j][r] + bias) * scl);
    }
  } else {
    // Tr[f_local][qi_local]
#pragma unroll
    for (int j = 0; j < 4; ++j) {
      const int fl_ = wn * 64 + j * 16 + l15;
      const float bias = qkv_b[n0 + fl_];
#pragma unroll
      for (int i = 0; i < 4; ++i)
#pragma unroll
        for (int r = 0; r < 4; ++r)
          u.Tr[fl_][wm * 64 + i * 16 + l4 * 4 + r] = (f16)(acc[i][j][r] + bias);
    }
  }
  __syncthreads();

  // read back 16B units, store wide. 2048 units, 8 per thread; 16-lane groups
  // cover one Tr row -> global runs of 96B (q/k) / 128B (vt). 8-unit spans
  // never straddle head (48%8==0) or batch (784%8==0) boundaries.
#pragma unroll
  for (int c = 0; c < 8; ++c) {
    const int v = c * 256 + t;
    const int rr = v >> 4, u16 = v & 15;
    if (sec < 2) {
      const int qi_l = rr, f_l = u16 * 8;
      const int fr = n0 + f_l - sec * CDIM;
      const int hh = fr / HD, d = fr - hh * HD;
      const int mm = m0 + qi_l, b = mm / NQ, tok = mm - b * NQ;
      f16* dst = (sec == 0 ? qh : kh) +
                 ((size_t)(b * NHEADS + hh) * NQ + tok) * HD + d;
      *(f16x8*)dst = *(const f16x8*)&u.Tr[qi_l][f_l];
    } else {
      const int f_l = rr, qi0 = u16 * 8;
      const int fr = n0 + f_l - 2 * CDIM;
      const int hh = fr / HD, d = fr - hh * HD;
      const int mm = m0 + qi0, b = mm / NQ, tok = mm - b * NQ;
      f16* dst = vt + ((size_t)(b * NHEADS + hh) * HD + d) * NQPAD + tok;
      *(f16x8*)dst = *(const f16x8*)&u.Tr[f_l][qi0];
    }
  }
}

// ---------------- Kernel B: fused flash attention (no-max softmax) ----------------
// 128 q-rows per block; q/k packed [bh][tok][48]; QK^T runs k=0..63 with
// LDS-zeroed pad chunks. K/V LDS tiles are 64-col with XOR-chunk swizzle
// (chunk ^= row&7, applied on BOTH write and read) -> conflict-free
// ds_read_b128 (was ~8-way at stride 72). Q hoisted to regs; Qs recycled as
// Ps (stride 68); K/V staging reg-prefetched.
__global__ __launch_bounds__(256) void flash_kernel(
    const f16* __restrict__ qh, const f16* __restrict__ kh,
    const f16* __restrict__ vt, f16* __restrict__ o16) {
  __shared__ f16 PQ[128 * 72];     // 18432 B: Qs[128][72]; recycled as Ps[4][32][68]
  __shared__ f16 Ks[64][64];       // 8192 B, XOR-chunk swizzled
  __shared__ f16 Vts[48][64];      // 6144 B, XOR-chunk swizzled

  f16 (*Qs)[72] = (f16(*)[72])PQ;
  f16 (*Ps)[32][68] = (f16(*)[32][68])PQ;

  const int t = threadIdx.x;
  const int lane = t & 63, w = t >> 6;
  const int quad = lane >> 4, l15 = lane & 15;
  const int q0 = blockIdx.x * 128;
  const int bh = blockIdx.y;

  const f16* qg = qh + (size_t)bh * NQ * HD;
  const f16* kg = kh + (size_t)bh * NQ * HD;
  const f16* vg = vt + (size_t)bh * HD * NQPAD;

  // ---- zero pads: Qs cols 48..63; Ks pre-swizzle chunks 6,7 ----
  {
    const f16x8 z8 = {};
    *(f16x8*)&Qs[t >> 1][48 + (t & 1) * 8] = z8;
    if (t < 128) {
      const int row = t >> 1, zc = 6 + (t & 1);
      *(f16x8*)&Ks[row][(zc ^ (row & 7)) * 8] = z8;
    }
  }

  // ---- stage Q tile: 128 rows x 48 cols (6 segs of 16B) ----
#pragma unroll
  for (int c = 0; c < 3; ++c) {
    const int u = t + c * 256;  // < 768
    const int row = u / 6, seg = u % 6;
    const int gr = min(q0 + row, NQ - 1);
    *(f16x8*)&Qs[row][seg * 8] =
        *(const f16x8*)(qg + (size_t)gr * HD + seg * 8);
  }
  __syncthreads();

  // ---- hoist Q fragments (Qs LDS is recycled as Ps after this) ----
  f16x8 qf0[2], qf1[2];
#pragma unroll
  for (int qa = 0; qa < 2; ++qa) {
    const int row = w * 32 + qa * 16 + l15;
    qf0[qa] = *(const f16x8*)&Qs[row][quad * 8];
    qf1[qa] = *(const f16x8*)&Qs[row][32 + quad * 8];
  }

  // ---- staging plan: 768 16B-units per K/V tile = 3 per thread ----
  const f16* gp[3];
  f16* lp[3];
  int step[3];
#pragma unroll
  for (int c = 0; c < 3; ++c) {
    const int u = t + c * 256;
    if (u < 384) {  // K: 64 rows x 6 segs (cols 0..47), swizzled dest
      const int row = u / 6, seg = u % 6;
      gp[c] = kg + (size_t)row * HD + seg * 8;
      lp[c] = &Ks[row][(seg ^ (row & 7)) * 8];
      step[c] = 64 * HD;
    } else {        // V^T: 48 rows x 8 segs, swizzled dest
      const int uv = u - 384;
      const int row = uv >> 3, seg = uv & 7;
      gp[c] = vg + (size_t)row * NQPAD + seg * 8;
      lp[c] = &Vts[row][(seg ^ (row & 7)) * 8];
      step[c] = 64;
    }
  }

  // prologue: issue tile 0 loads
  f16x8 rg[3];
#pragma unroll
  for (int c = 0; c < 3; ++c) {
    rg[c] = *(const f16x8*)gp[c];
    gp[c] += step[c];
  }

  f32x4 accO[2][3] = {};
  float l_[2][4] = {};

  for (int kt = 0; kt < 13; ++kt) {
    // commit staged tile kt to LDS
#pragma unroll
    for (int c = 0; c < 3; ++c) *(f16x8*)lp[c] = rg[c];
    __syncthreads();
    // issue tile kt+1 loads; HBM latency hides under compute below
    if (kt < 12) {
#pragma unroll
      for (int c = 0; c < 3; ++c) {
        rg[c] = *(const f16x8*)gp[c];
        gp[c] += step[c];
      }
    }

    // ---- QK^T (k=0..63, pad zeros) fused with exp2 + row-sum + P store ----
    const bool last = (kt == 12);
#pragma unroll
    for (int j = 0; j < 4; ++j) {
      const int krow = j * 16 + l15, ksw = krow & 7;
      const f16x8 b0 = *(const f16x8*)&Ks[krow][(quad ^ ksw) * 8];
      const f16x8 b1 = *(const f16x8*)&Ks[krow][((4 + quad) ^ ksw) * 8];
      f32x4 z0 = {}, z1 = {};
      z0 = __builtin_amdgcn_mfma_f32_16x16x32_f16(qf0[0], b0, z0, 0, 0, 0);
      const f32x4 sj0 = __builtin_amdgcn_mfma_f32_16x16x32_f16(qf1[0], b1, z0, 0, 0, 0);
      z1 = __builtin_amdgcn_mfma_f32_16x16x32_f16(qf0[1], b0, z1, 0, 0, 0);
      const f32x4 sj1 = __builtin_amdgcn_mfma_f32_16x16x32_f16(qf1[1], b1, z1, 0, 0, 0);
      const bool msk = last && (j >= 1);  // keys >= 784
#pragma unroll
      for (int r = 0; r < 4; ++r) {
        const float p0 = msk ? 0.f : fast_exp2(sj0[r]);
        const float p1 = msk ? 0.f : fast_exp2(sj1[r]);
        l_[0][r] += p0;
        l_[1][r] += p1;
        Ps[w][quad * 4 + r][j * 16 + l15] = (f16)p0;
        Ps[w][16 + quad * 4 + r][j * 16 + l15] = (f16)p1;
      }
    }

    // ---- P fragments (8B-aligned b64 pairs; stride 68 spreads banks) ----
    f16x8 ap0[2], ap1[2];
#pragma unroll
    for (int qa = 0; qa < 2; ++qa) {
      const int row = qa * 16 + l15;
      const f16x4 a0 = *(const f16x4*)&Ps[w][row][quad * 8];
      const f16x4 a1 = *(const f16x4*)&Ps[w][row][quad * 8 + 4];
      const f16x4 a2 = *(const f16x4*)&Ps[w][row][32 + quad * 8];
      const f16x4 a3 = *(const f16x4*)&Ps[w][row][32 + quad * 8 + 4];
      ap0[qa] = __builtin_shufflevector(a0, a1, 0, 1, 2, 3, 4, 5, 6, 7);
      ap1[qa] = __builtin_shufflevector(a2, a3, 0, 1, 2, 3, 4, 5, 6, 7);
    }

    // ---- PV ----
#pragma unroll
    for (int jn = 0; jn < 3; ++jn) {
      const int vrow = jn * 16 + l15, vsw = vrow & 7;
      const f16x8 v0 = *(const f16x8*)&Vts[vrow][(quad ^ vsw) * 8];
      const f16x8 v1 = *(const f16x8*)&Vts[vrow][((4 + quad) ^ vsw) * 8];
#pragma unroll
      for (int qa = 0; qa < 2; ++qa) {
        accO[qa][jn] =
            __builtin_amdgcn_mfma_f32_16x16x32_f16(ap0[qa], v0, accO[qa][jn], 0, 0, 0);
        accO[qa][jn] =
            __builtin_amdgcn_mfma_f32_16x16x32_f16(ap1[qa], v1, accO[qa][jn], 0, 0, 0);
      }
    }
    __syncthreads();
  }

  // ---- normalize + store ----
  const int b = bh >> 3, hh = bh & 7;
#pragma unroll
  for (int qa = 0; qa < 2; ++qa) {
#pragma unroll
    for (int r = 0; r < 4; ++r) {
      float rs = l_[qa][r];
      rs += __shfl_xor(rs, 1);
      rs += __shfl_xor(rs, 2);
      rs += __shfl_xor(rs, 4);
      rs += __shfl_xor(rs, 8);
      const int qrow = q0 + w * 32 + qa * 16 + quad * 4 + r;
      if (qrow < NQ) {
        const float inv = 1.f / rs;
#pragma unroll
        for (int jn = 0; jn < 3; ++jn)
          o16[((size_t)(b * NQ + qrow)) * CDIM + hh * HD + jn * 16 + l15] =
              (f16)(accO[qa][jn][r] * inv);
      }
    }
  }
}

// ---------------- Kernel C1: per-row LN stats for the 4 upsample phases ----------------
// u_pq = o * lp_w[:,pq] + lp_b; stats[m][pq] = (mu, rstd). One wave per row.
__global__ __launch_bounds__(256) void stats_kernel(
    const f16* __restrict__ o16, const float* __restrict__ lp_w,
    const float* __restrict__ lp_b, float* __restrict__ stats) {
  const int m = blockIdx.x * 4 + (threadIdx.x >> 6);
  const int lane = threadIdx.x & 63;
  float s[4] = {}, ss[4] = {};
#pragma unroll
  for (int i = 0; i < 6; ++i) {
    const int c = lane + i * 64;
    const float ov = (float)o16[(size_t)m * CDIM + c];
    const float4 w4 = *(const float4*)(lp_w + c * 4);
    const float bb = lp_b[c];
    const float u0 = ov * w4.x + bb;
    const float u1 = ov * w4.y + bb;
    const float u2 = ov * w4.z + bb;
    const float u3 = ov * w4.w + bb;
    s[0] += u0; ss[0] += u0 * u0;
    s[1] += u1; ss[1] += u1 * u1;
    s[2] += u2; ss[2] += u2 * u2;
    s[3] += u3; ss[3] += u3 * u3;
  }
#pragma unroll
  for (int pq = 0; pq < 4; ++pq) {
    s[pq] = waveSum(s[pq]);
    ss[pq] = waveSum(ss[pq]);
  }
  if (lane < 4) {
    const float mu = s[lane] * (1.f / CDIM);
    const float var = ss[lane] * (1.f / CDIM) - mu * mu;
    stats[m * 8 + lane * 2] = mu;
    stats[m * 8 + lane * 2 + 1] = rsqrtf(var + LN_EPS);
  }
}

// ---------------- Kernel D: fused upsample+LN+proj GEMM ----------------
// G = o16 @ wq^T  (M=12544, N=1536, K=384); out row (m,pq) -> pixel scatter.
// 1D grid 1176 = 98 m-tiles x 12 n-tiles, XCD-chunk swizzled; each block's
// 128-col range lies in exactly one pq (384=3*128). out stores are 64B
// f32 runs (acceptable granule).
__global__ __launch_bounds__(256) void projfused_kernel(
    const f16* __restrict__ o16, const f16* __restrict__ wq,
    const float* __restrict__ stats, const float* __restrict__ cvec,
    float* __restrict__ out) {
  __shared__ f16 As[2 * 128 * 32];
  __shared__ f16 Bs[2 * 128 * 32];
  const int lin = xcd_chunk_lin(blockIdx.x, 1176);
  const int m0 = (lin / 12) * 128, n0 = (lin % 12) * 128;
  f32x4 acc[4][4] = {};
  mfma_tile_gemm_db(o16, wq, m0, n0, CDIM, acc, As, Bs);

  const int t = threadIdx.x, lane = t & 63, w = t >> 6;
  const int wm = w >> 1, wn = w & 1;
  const int l15 = lane & 15, l4 = lane >> 4;
  const int pq = n0 / CDIM;  // uniform per block
  const int p = pq >> 1, q = pq & 1;
  const int c0 = n0 - pq * CDIM;

  float C1[4], C2[4], C3[4];
#pragma unroll
  for (int j = 0; j < 4; ++j) {
    const int col = c0 + wn * 64 + j * 16 + l15;
    C1[j] = cvec[col];
    C2[j] = cvec[CDIM + col];
    C3[j] = cvec[2 * CDIM + col];
  }

#pragma unroll
  for (int i = 0; i < 4; ++i) {
#pragma unroll
    for (int r = 0; r < 4; ++r) {
      const int m = m0 + wm * 64 + i * 16 + l4 * 4 + r;
      const int b = m / NQ, n = m % NQ;
      const int hi2 = n / 28, wi2 = n % 28;
      const float mu = stats[m * 8 + pq * 2];
      const float rstd = stats[m * 8 + pq * 2 + 1];
      const int pix = (hi2 * 2 + p) * HWD + (wi2 * 2 + q);
      float* orow = out + ((size_t)(b * NPIX + pix)) * CDIM;
#pragma unroll
      for (int j = 0; j < 4; ++j) {
        const int col = c0 + wn * 64 + j * 16 + l15;
        orow[col] = rstd * (acc[i][j][r] * WUNSCALE + C1[j] - mu * C2[j]) + C3[j];
      }
    }
  }
}

extern "C" void kernel_launch(void* const* d_in, const int* in_sizes, int n_in,
                              void* d_out, int out_size, void* d_ws,
                              size_t ws_size, hipStream_t stream) {
  const float* x      = (const float*)d_in[0];
  const float* qkv_w  = (const float*)d_in[1];
  const float* qkv_b  = (const float*)d_in[2];
  const float* proj_w = (const float*)d_in[3];
  const float* proj_b = (const float*)d_in[4];
  const float* lp_w   = (const float*)d_in[5];
  const float* lp_b   = (const float*)d_in[6];
  const float* ln_w   = (const float*)d_in[7];
  const float* ln_b   = (const float*)d_in[8];
  float* out = (float*)d_out;

  // workspace layout (float offsets), total ~13.7M floats = 55 MB
  float* ws = (float*)d_ws;
  f16* o16 = (f16*)ws;                        // [12544][384]   4,816,896 f16 (2,408,448 fl)
  float* zreg = ws + 2408448;                 // region: qh,kh,vt
  f16* qh = (f16*)zreg;                       // [128][784][48] 4,816,896 f16
  f16* kh = qh + (size_t)128 * NQ * HD;       // [128][784][48] 4,816,896 f16
  f16* vt = kh + (size_t)128 * NQ * HD;       // [128][48][832] 5,111,808 f16
  float* rest = zreg + 7372800;               // end of q/k/v region
  f16* xp = (f16*)rest;                       // [12544][384]   4,816,896 f16
  f16* qkv_wh = xp + (size_t)12544 * CDIM;    // [1152][384]      442,368 f16
  float* rest2 = rest + 2408448 + 221184;
  f16* wq = (f16*)rest2;                      // [1536][384]    2,359,296 f16 (1,179,648 fl)
  float* cvec = rest2 + 1179648;              // [3][384]           1,152 fl
  float* stats = cvec + 1152;                 // [12544][4][2]    100,352 fl

  // 1) fused prep: pool_cast + w_cast + vt-pad zero + wprep + cvec
  prep_kernel<<<dim3(5952), 256, 0, stream>>>(x, xp, qkv_w, qkv_wh, vt, proj_w,
                                              lp_w, ln_w, lp_b, ln_b, proj_b,
                                              wq, cvec);

  // 2) pooled qkv GEMM (fp16 MFMA)
  qkv_mfma_kernel<<<dim3(882), 256, 0, stream>>>(xp, qkv_wh, qkv_b, qh, kh, vt);

  // 3) fused flash attention -> fp16 o (128 q-rows/block)
  flash_kernel<<<dim3(7, 128), 256, 0, stream>>>(qh, kh, vt, o16);

  // 4) LN stats
  stats_kernel<<<dim3(3136), 256, 0, stream>>>(o16, lp_w, lp_b, stats);

  // 5) fused upsample+LN+proj GEMM
  projfused_kernel<<<dim3(1176), 256, 0, stream>>>(o16, wq, stats, cvec, out);
}

// Round 8
// 242.225 us; speedup vs baseline: 1.1914x; 1.0023x over previous
//
#include <hip/hip_runtime.h>
#include <math.h>

#define CDIM 384
#define NHEADS 8
#define HD 48
#define NQ 784      // 28*28 pooled tokens
#define NQPAD 832   // 13*64, zero-padded k/n extent for V^T
#define NB 16
#define HWD 56
#define NPIX 3136   // 56*56
// 48^-0.5 * log2(e): scores land in exp2 domain, softmax uses raw v_exp_f32
#define QK_SCALE (0.14433756729740643f * 1.4426950408889634f)
#define LN_EPS 1e-5f
#define WSCALE 16.0f     // fold into W_pq to stay clear of f16 denormals
#define WUNSCALE 0.0625f

typedef _Float16 f16;
typedef _Float16 f16x4 __attribute__((ext_vector_type(4)));
typedef _Float16 f16x8 __attribute__((ext_vector_type(8)));
typedef float f32x4 __attribute__((ext_vector_type(4)));

// ---------------- wave/block reduction helpers ----------------
__device__ __forceinline__ float waveSum(float v) {
#pragma unroll
  for (int o = 32; o > 0; o >>= 1) v += __shfl_xor(v, o);
  return v;
}

__device__ __forceinline__ float fast_exp2(float x) {
#if __has_builtin(__builtin_amdgcn_exp2f)
  return __builtin_amdgcn_exp2f(x);
#else
  return __expf(x * 0.6931471805599453f);
#endif
}

// async global->LDS 16B copy (wave-uniform lds base + lane*16 scatter)
__device__ __forceinline__ void gload16(const void* g, void* l) {
  __builtin_amdgcn_global_load_lds(
      (const __attribute__((address_space(1))) void*)g,
      (__attribute__((address_space(3))) void*)l, 16, 0, 0);
}

// chunked-bijective XCD swizzle (m204): dispatch id b -> linear tile id such
// that blocks resident on one XCD (b%8 round-robin) cover a contiguous chunk
// of tiles -> per-XCD L2 working set stays small.
__device__ __forceinline__ int xcd_chunk_lin(int b, int nwg) {
  const int c = b & 7, s = b >> 3;
  const int q = nwg >> 3, r = nwg & 7;
  const int off = (c < r) ? c * (q + 1) : r * (q + 1) + (c - r) * q;
  return off + s;
}

// ---------------- Kernel P: fused prep (launch-count reduction) ----------------
// Branch ladder over independent jobs, all input-only:
//  [0,4704)      pool_cast: pooled-gather x -> fp16 A [12544,384]
//  [4704,5136)   w_cast: qkv_w -> f16
//  [5136,5280)   zero vt pad tokens (784..831 per [bh][d] row; 36864 float4)
//  [5280,5856)   wprep: W_pq = proj_w * lp_w[:,pq] * ln_w * WSCALE -> f16
//  [5856,5952)   cvec: 3 constant vectors (4 j-rows per block, 1 per wave)
__global__ __launch_bounds__(256) void prep_kernel(
    const float* __restrict__ x, f16* __restrict__ xp,
    const float* __restrict__ qkv_w, f16* __restrict__ qkv_wh,
    f16* __restrict__ vt, const float* __restrict__ pw,
    const float* __restrict__ lpw, const float* __restrict__ lnw,
    const float* __restrict__ lp_b, const float* __restrict__ ln_b,
    const float* __restrict__ pb, f16* __restrict__ wq,
    float* __restrict__ cvec) {
  const int blk = blockIdx.x, t = threadIdx.x;
  if (blk < 4704) {
    const int i = (blk * 256 + t) * 4;
    const int row = i / CDIM, col = i % CDIM;
    const int b = row / NQ, qi = row % NQ;
    const int hi = qi / 28, wi = qi % 28;
    const float4 v =
        *(const float4*)(x + ((size_t)(b * NPIX + hi * 112 + wi * 2)) * CDIM + col);
    f16x4 h;
    h.x = (f16)v.x; h.y = (f16)v.y; h.z = (f16)v.z; h.w = (f16)v.w;
    *(f16x4*)(xp + i) = h;
  } else if (blk < 5136) {
    const int i = ((blk - 4704) * 256 + t) * 4;  // < 1152*384
    const float4 v = *(const float4*)(qkv_w + i);
    f16x4 h;
    h.x = (f16)v.x; h.y = (f16)v.y; h.z = (f16)v.z; h.w = (f16)v.w;
    *(f16x4*)(qkv_wh + i) = h;
  } else if (blk < 5280) {
    const int idx = (blk - 5136) * 256 + t;  // < 36864
    const int row = idx / 6, off = idx % 6;  // row < 6144 = 128*48
    float4* p = (float4*)vt + (size_t)row * 104 + 98 + off;  // 832*2B=104 f4
    *p = make_float4(0.f, 0.f, 0.f, 0.f);
  } else if (blk < 5856) {
    const int i4 = ((blk - 5280) * 256 + t) * 4;  // < 1536*384
    const int f = i4 / CDIM, c = i4 % CDIM;
    const int pq = f / CDIM, j = f % CDIM;
    const float4 wv = *(const float4*)(pw + (size_t)j * CDIM + c);
    const float4 ln = *(const float4*)(lnw + c);
    f16x4 h;
    h.x = (f16)(wv.x * lpw[(c + 0) * 4 + pq] * ln.x * WSCALE);
    h.y = (f16)(wv.y * lpw[(c + 1) * 4 + pq] * ln.y * WSCALE);
    h.z = (f16)(wv.z * lpw[(c + 2) * 4 + pq] * ln.z * WSCALE);
    h.w = (f16)(wv.w * lpw[(c + 3) * 4 + pq] * ln.w * WSCALE);
    *(f16x4*)(wq + i4) = h;
  } else {
    const int j = (blk - 5856) * 4 + (t >> 6);  // < 384
    const int lane = t & 63;
    float a1 = 0.f, a2 = 0.f, a3 = 0.f;
#pragma unroll
    for (int i = 0; i < 6; ++i) {
      const int c = lane + i * 64;
      const float wv = pw[(size_t)j * CDIM + c];
      a1 += lp_b[c] * lnw[c] * wv;
      a2 += lnw[c] * wv;
      a3 += ln_b[c] * wv;
    }
    a1 = waveSum(a1);
    a2 = waveSum(a2);
    a3 = waveSum(a3);
    if (lane == 0) {
      cvec[j] = a1;
      cvec[CDIM + j] = a2;
      cvec[2 * CDIM + j] = a3 + pb[j];
    }
  }
}

// ---------------- shared MFMA tile GEMM body (3-deep counted-vmcnt pipeline) ----------------
// C(128x128 tile at m0,n0) = A[M,384] @ B[N,384]^T, fp16 in, fp32 acc.
// T3/T4 minimum recipe: tiles k and k+1 always in flight; at iter k wait
// s_waitcnt vmcnt(4) (tile k's 4 gloads done, tile k+1's 4 still flying),
// raw s_barrier, then issue tile k+2 into buf (k-1)%3 (safe: all waves past
// the barrier => done reading it). Load latency budget = 2 compute phases.
// As/Bs: 3 buffers of 128x32 f16 each (24 KB each, 48 KB total).
__device__ __forceinline__ void mfma_tile_gemm_pipe(
    const f16* __restrict__ A, const f16* __restrict__ B, int m0, int n0,
    f32x4 (&acc)[4][4], f16* As, f16* Bs) {
  const int t = threadIdx.x;
  const int lane = t & 63, w = t >> 6;
  const int wm = w >> 1, wn = w & 1;
  const int l15 = lane & 15, l4 = lane >> 4;
  const int rowS = t >> 2;
  const int kb = (t & 3) * 16;
  char* AsB = (char*)As;
  char* BsB = (char*)Bs;
  const char* Ag = (const char*)A + ((size_t)(m0 + rowS) * CDIM) * 2 + kb;
  const char* Bg = (const char*)B + ((size_t)(n0 + rowS) * CDIM) * 2 + kb;
  const size_t row64 = (size_t)64 * CDIM * 2;

#define ISSUE(kk)                                           \
  do {                                                      \
    const int bofs = ((kk) % 3) * 8192;                     \
    const char* Ag2 = Ag + (size_t)(kk) * 64;               \
    const char* Bg2 = Bg + (size_t)(kk) * 64;               \
    gload16(Ag2, AsB + bofs + t * 16);                      \
    gload16(Ag2 + row64, AsB + bofs + 4096 + t * 16);       \
    gload16(Bg2, BsB + bofs + t * 16);                      \
    gload16(Bg2 + row64, BsB + bofs + 4096 + t * 16);       \
  } while (0)

  ISSUE(0);
  ISSUE(1);

#pragma unroll
  for (int k = 0; k < 12; ++k) {
    if (k < 11)
      asm volatile("s_waitcnt vmcnt(4)" ::: "memory");
    else
      asm volatile("s_waitcnt vmcnt(0)" ::: "memory");
    __builtin_amdgcn_s_barrier();
    __builtin_amdgcn_sched_barrier(0);
    if (k + 2 < 12) ISSUE(k + 2);
    const char* Ab = AsB + (k % 3) * 8192;
    const char* Bb = BsB + (k % 3) * 8192;
    f16x8 af[4], bf[4];
#pragma unroll
    for (int i = 0; i < 4; ++i)
      af[i] = *(const f16x8*)(Ab + ((wm * 64 + i * 16 + l15) * 64 + l4 * 16));
#pragma unroll
    for (int j = 0; j < 4; ++j)
      bf[j] = *(const f16x8*)(Bb + ((wn * 64 + j * 16 + l15) * 64 + l4 * 16));
#pragma unroll
    for (int i = 0; i < 4; ++i)
#pragma unroll
      for (int j = 0; j < 4; ++j)
        acc[i][j] =
            __builtin_amdgcn_mfma_f32_16x16x32_f16(af[i], bf[j], acc[i][j], 0, 0, 0);
  }
#undef ISSUE
}

// ---------------- Kernel A: QKV GEMM (fp16 MFMA) ----------------
// 1D grid 882 = 98 m-tiles x 9 n-tiles, XCD-chunk swizzled. Each n-tile lies
// in exactly one of q/k/v. Epilogue transposes the 128x128 result through LDS
// so all global stores are 16B vectors (removes the 2-byte scatter that
// pinned this kernel at ~53us across three K-loop structures).
__global__ __launch_bounds__(256) void qkv_mfma_kernel(
    const f16* __restrict__ xp, const f16* __restrict__ wh,
    const float* __restrict__ qkv_b, f16* __restrict__ qh,
    f16* __restrict__ kh, f16* __restrict__ vt) {
  __shared__ union SU {
    struct { f16 As[3 * 128 * 32]; f16 Bs[3 * 128 * 32]; } s;  // 48 KB
    f16 Tr[128][136];                                          // 34 KB
  } u;
  const int lin = xcd_chunk_lin(blockIdx.x, 882);
  const int m0 = (lin / 9) * 128, n0 = (lin % 9) * 128;
  f32x4 acc[4][4] = {};
  mfma_tile_gemm_pipe(xp, wh, m0, n0, acc, u.s.As, u.s.Bs);

  const int t = threadIdx.x, lane = t & 63, w = t >> 6;
  const int wm = w >> 1, wn = w & 1;
  const int l15 = lane & 15, l4 = lane >> 4;
  const int sec = n0 / CDIM;  // 0=q, 1=k, 2=v (block-uniform)
  const float scl = (sec == 0) ? QK_SCALE : 1.f;

  __syncthreads();  // all LDS reads of As/Bs complete before aliasing as Tr

  if (sec < 2) {
    // Tr[qi_local][f_local]
#pragma unroll
    for (int j = 0; j < 4; ++j) {
      const int fl_ = wn * 64 + j * 16 + l15;
      const float bias = qkv_b[n0 + fl_];
#pragma unroll
      for (int i = 0; i < 4; ++i)
#pragma unroll
        for (int r = 0; r < 4; ++r)
          u.Tr[wm * 64 + i * 16 + l4 * 4 + r][fl_] =
              (f16)((acc[i][j][r] + bias) * scl);
    }
  } else {
    // Tr[f_local][qi_local]
#pragma unroll
    for (int j = 0; j < 4; ++j) {
      const int fl_ = wn * 64 + j * 16 + l15;
      const float bias = qkv_b[n0 + fl_];
#pragma unroll
      for (int i = 0; i < 4; ++i)
#pragma unroll
        for (int r = 0; r < 4; ++r)
          u.Tr[fl_][wm * 64 + i * 16 + l4 * 4 + r] = (f16)(acc[i][j][r] + bias);
    }
  }
  __syncthreads();

  // read back 16B units, store wide. 2048 units, 8 per thread; 16-lane groups
  // cover one Tr row -> global runs of 96B (q/k) / 128B (vt). 8-unit spans
  // never straddle head (48%8==0) or batch (784%8==0) boundaries.
#pragma unroll
  for (int c = 0; c < 8; ++c) {
    const int v = c * 256 + t;
    const int rr = v >> 4, u16 = v & 15;
    if (sec < 2) {
      const int qi_l = rr, f_l = u16 * 8;
      const int fr = n0 + f_l - sec * CDIM;
      const int hh = fr / HD, d = fr - hh * HD;
      const int mm = m0 + qi_l, b = mm / NQ, tok = mm - b * NQ;
      f16* dst = (sec == 0 ? qh : kh) +
                 ((size_t)(b * NHEADS + hh) * NQ + tok) * HD + d;
      *(f16x8*)dst = *(const f16x8*)&u.Tr[qi_l][f_l];
    } else {
      const int f_l = rr, qi0 = u16 * 8;
      const int fr = n0 + f_l - 2 * CDIM;
      const int hh = fr / HD, d = fr - hh * HD;
      const int mm = m0 + qi0, b = mm / NQ, tok = mm - b * NQ;
      f16* dst = vt + ((size_t)(b * NHEADS + hh) * HD + d) * NQPAD + tok;
      *(f16x8*)dst = *(const f16x8*)&u.Tr[f_l][qi0];
    }
  }
}

// ---------------- Kernel B: fused flash attention (no-max softmax) ----------------
// R6-proven layout (51.1us): 128 q-rows per block; q/k packed [bh][tok][48];
// QK^T runs k=0..63 with LDS-zeroed pad cols 48..63; Ks/Vts stride-72 rows
// (the R7 XOR-swizzle cut conflicts 4.4x but COST 4.7us in VALU addr math —
// reverted). Q hoisted to regs; Qs recycled as Ps; K/V staging reg-prefetched.
__global__ __launch_bounds__(256) void flash_kernel(
    const f16* __restrict__ qh, const f16* __restrict__ kh,
    const f16* __restrict__ vt, f16* __restrict__ o16) {
  __shared__ f16 PQ[128 * 72];     // 18432 B: Qs[128][72]; recycled as Ps[4][32][68]
  __shared__ f16 Ks[64][72];       // 9216 B
  __shared__ f16 Vts[48][72];      // 6912 B

  f16 (*Qs)[72] = (f16(*)[72])PQ;
  f16 (*Ps)[32][68] = (f16(*)[32][68])PQ;

  const int t = threadIdx.x;
  const int lane = t & 63, w = t >> 6;
  const int quad = lane >> 4, l15 = lane & 15;
  const int q0 = blockIdx.x * 128;
  const int bh = blockIdx.y;

  const f16* qg = qh + (size_t)bh * NQ * HD;
  const f16* kg = kh + (size_t)bh * NQ * HD;
  const f16* vg = vt + (size_t)bh * HD * NQPAD;

  // ---- zero k-pad cols 48..63 of Qs (256 units) and Ks (128 units) ----
  {
    const f16x8 z8 = {};
    *(f16x8*)&Qs[t >> 1][48 + (t & 1) * 8] = z8;
    if (t < 128) *(f16x8*)&Ks[t >> 1][48 + (t & 1) * 8] = z8;
  }

  // ---- stage Q tile: 128 rows x 48 cols (6 segs of 16B) ----
#pragma unroll
  for (int c = 0; c < 3; ++c) {
    const int u = t + c * 256;  // < 768
    const int row = u / 6, seg = u % 6;
    const int gr = min(q0 + row, NQ - 1);
    *(f16x8*)&Qs[row][seg * 8] =
        *(const f16x8*)(qg + (size_t)gr * HD + seg * 8);
  }
  __syncthreads();

  // ---- hoist Q fragments (Qs LDS is recycled as Ps after this) ----
  f16x8 qf0[2], qf1[2];
#pragma unroll
  for (int qa = 0; qa < 2; ++qa) {
    const int row = w * 32 + qa * 16 + l15;
    qf0[qa] = *(const f16x8*)&Qs[row][quad * 8];
    qf1[qa] = *(const f16x8*)&Qs[row][32 + quad * 8];
  }

  // ---- staging plan: 768 16B-units per K/V tile = 3 per thread ----
  const f16* gp[3];
  f16* lp[3];
  int step[3];
#pragma unroll
  for (int c = 0; c < 3; ++c) {
    const int u = t + c * 256;
    if (u < 384) {  // K: 64 rows x 6 segs (cols 0..47)
      const int row = u / 6, seg = u % 6;
      gp[c] = kg + (size_t)row * HD + seg * 8;
      lp[c] = &Ks[row][seg * 8];
      step[c] = 64 * HD;
    } else {        // V^T: 48 rows x 8 segs
      const int uv = u - 384;
      const int row = uv >> 3, seg = uv & 7;
      gp[c] = vg + (size_t)row * NQPAD + seg * 8;
      lp[c] = &Vts[row][seg * 8];
      step[c] = 64;
    }
  }

  // prologue: issue tile 0 loads
  f16x8 rg[3];
#pragma unroll
  for (int c = 0; c < 3; ++c) {
    rg[c] = *(const f16x8*)gp[c];
    gp[c] += step[c];
  }

  f32x4 accO[2][3] = {};
  float l_[2][4] = {};

  for (int kt = 0; kt < 13; ++kt) {
    // commit staged tile kt to LDS (cols 0..47 only; pads stay zero)
#pragma unroll
    for (int c = 0; c < 3; ++c) *(f16x8*)lp[c] = rg[c];
    __syncthreads();
    // issue tile kt+1 loads; HBM latency hides under compute below
    if (kt < 12) {
#pragma unroll
      for (int c = 0; c < 3; ++c) {
        rg[c] = *(const f16x8*)gp[c];
        gp[c] += step[c];
      }
    }

    // ---- QK^T (k=0..63, pad zeros) fused with exp2 + row-sum + P store ----
    const bool last = (kt == 12);
#pragma unroll
    for (int j = 0; j < 4; ++j) {
      const f16x8 b0 = *(const f16x8*)&Ks[j * 16 + l15][quad * 8];
      const f16x8 b1 = *(const f16x8*)&Ks[j * 16 + l15][32 + quad * 8];
      f32x4 z0 = {}, z1 = {};
      z0 = __builtin_amdgcn_mfma_f32_16x16x32_f16(qf0[0], b0, z0, 0, 0, 0);
      const f32x4 sj0 = __builtin_amdgcn_mfma_f32_16x16x32_f16(qf1[0], b1, z0, 0, 0, 0);
      z1 = __builtin_amdgcn_mfma_f32_16x16x32_f16(qf0[1], b0, z1, 0, 0, 0);
      const f32x4 sj1 = __builtin_amdgcn_mfma_f32_16x16x32_f16(qf1[1], b1, z1, 0, 0, 0);
      const bool msk = last && (j >= 1);  // keys >= 784
#pragma unroll
      for (int r = 0; r < 4; ++r) {
        const float p0 = msk ? 0.f : fast_exp2(sj0[r]);
        const float p1 = msk ? 0.f : fast_exp2(sj1[r]);
        l_[0][r] += p0;
        l_[1][r] += p1;
        Ps[w][quad * 4 + r][j * 16 + l15] = (f16)p0;
        Ps[w][16 + quad * 4 + r][j * 16 + l15] = (f16)p1;
      }
    }

    // ---- P fragments (8B-aligned b64 pairs; stride 68 spreads banks) ----
    f16x8 ap0[2], ap1[2];
#pragma unroll
    for (int qa = 0; qa < 2; ++qa) {
      const int row = qa * 16 + l15;
      const f16x4 a0 = *(const f16x4*)&Ps[w][row][quad * 8];
      const f16x4 a1 = *(const f16x4*)&Ps[w][row][quad * 8 + 4];
      const f16x4 a2 = *(const f16x4*)&Ps[w][row][32 + quad * 8];
      const f16x4 a3 = *(const f16x4*)&Ps[w][row][32 + quad * 8 + 4];
      ap0[qa] = __builtin_shufflevector(a0, a1, 0, 1, 2, 3, 4, 5, 6, 7);
      ap1[qa] = __builtin_shufflevector(a2, a3, 0, 1, 2, 3, 4, 5, 6, 7);
    }

    // ---- PV ----
#pragma unroll
    for (int jn = 0; jn < 3; ++jn) {
      const f16x8 v0 = *(const f16x8*)&Vts[jn * 16 + l15][quad * 8];
      const f16x8 v1 = *(const f16x8*)&Vts[jn * 16 + l15][32 + quad * 8];
#pragma unroll
      for (int qa = 0; qa < 2; ++qa) {
        accO[qa][jn] =
            __builtin_amdgcn_mfma_f32_16x16x32_f16(ap0[qa], v0, accO[qa][jn], 0, 0, 0);
        accO[qa][jn] =
            __builtin_amdgcn_mfma_f32_16x16x32_f16(ap1[qa], v1, accO[qa][jn], 0, 0, 0);
      }
    }
    __syncthreads();
  }

  // ---- normalize + store ----
  const int b = bh >> 3, hh = bh & 7;
#pragma unroll
  for (int qa = 0; qa < 2; ++qa) {
#pragma unroll
    for (int r = 0; r < 4; ++r) {
      float rs = l_[qa][r];
      rs += __shfl_xor(rs, 1);
      rs += __shfl_xor(rs, 2);
      rs += __shfl_xor(rs, 4);
      rs += __shfl_xor(rs, 8);
      const int qrow = q0 + w * 32 + qa * 16 + quad * 4 + r;
      if (qrow < NQ) {
        const float inv = 1.f / rs;
#pragma unroll
        for (int jn = 0; jn < 3; ++jn)
          o16[((size_t)(b * NQ + qrow)) * CDIM + hh * HD + jn * 16 + l15] =
              (f16)(accO[qa][jn][r] * inv);
      }
    }
  }
}

// ---------------- Kernel C1: per-row LN stats for the 4 upsample phases ----------------
// u_pq = o * lp_w[:,pq] + lp_b; stats[m][pq] = (mu, rstd). One wave per row.
__global__ __launch_bounds__(256) void stats_kernel(
    const f16* __restrict__ o16, const float* __restrict__ lp_w,
    const float* __restrict__ lp_b, float* __restrict__ stats) {
  const int m = blockIdx.x * 4 + (threadIdx.x >> 6);
  const int lane = threadIdx.x & 63;
  float s[4] = {}, ss[4] = {};
#pragma unroll
  for (int i = 0; i < 6; ++i) {
    const int c = lane + i * 64;
    const float ov = (float)o16[(size_t)m * CDIM + c];
    const float4 w4 = *(const float4*)(lp_w + c * 4);
    const float bb = lp_b[c];
    const float u0 = ov * w4.x + bb;
    const float u1 = ov * w4.y + bb;
    const float u2 = ov * w4.z + bb;
    const float u3 = ov * w4.w + bb;
    s[0] += u0; ss[0] += u0 * u0;
    s[1] += u1; ss[1] += u1 * u1;
    s[2] += u2; ss[2] += u2 * u2;
    s[3] += u3; ss[3] += u3 * u3;
  }
#pragma unroll
  for (int pq = 0; pq < 4; ++pq) {
    s[pq] = waveSum(s[pq]);
    ss[pq] = waveSum(ss[pq]);
  }
  if (lane < 4) {
    const float mu = s[lane] * (1.f / CDIM);
    const float var = ss[lane] * (1.f / CDIM) - mu * mu;
    stats[m * 8 + lane * 2] = mu;
    stats[m * 8 + lane * 2 + 1] = rsqrtf(var + LN_EPS);
  }
}

// ---------------- Kernel D: fused upsample+LN+proj GEMM ----------------
// G = o16 @ wq^T  (M=12544, N=1536, K=384); out row (m,pq) -> pixel scatter.
// 1D grid 1176 = 98 m-tiles x 12 n-tiles, XCD-chunk swizzled; each block's
// 128-col range lies in exactly one pq (384=3*128). out stores are 64B
// f32 runs (acceptable granule).
__global__ __launch_bounds__(256) void projfused_kernel(
    const f16* __restrict__ o16, const f16* __restrict__ wq,
    const float* __restrict__ stats, const float* __restrict__ cvec,
    float* __restrict__ out) {
  __shared__ f16 As[3 * 128 * 32];
  __shared__ f16 Bs[3 * 128 * 32];
  const int lin = xcd_chunk_lin(blockIdx.x, 1176);
  const int m0 = (lin / 12) * 128, n0 = (lin % 12) * 128;
  f32x4 acc[4][4] = {};
  mfma_tile_gemm_pipe(o16, wq, m0, n0, acc, As, Bs);

  const int t = threadIdx.x, lane = t & 63, w = t >> 6;
  const int wm = w >> 1, wn = w & 1;
  const int l15 = lane & 15, l4 = lane >> 4;
  const int pq = n0 / CDIM;  // uniform per block
  const int p = pq >> 1, q = pq & 1;
  const int c0 = n0 - pq * CDIM;

  float C1[4], C2[4], C3[4];
#pragma unroll
  for (int j = 0; j < 4; ++j) {
    const int col = c0 + wn * 64 + j * 16 + l15;
    C1[j] = cvec[col];
    C2[j] = cvec[CDIM + col];
    C3[j] = cvec[2 * CDIM + col];
  }

#pragma unroll
  for (int i = 0; i < 4; ++i) {
#pragma unroll
    for (int r = 0; r < 4; ++r) {
      const int m = m0 + wm * 64 + i * 16 + l4 * 4 + r;
      const int b = m / NQ, n = m % NQ;
      const int hi2 = n / 28, wi2 = n % 28;
      const float mu = stats[m * 8 + pq * 2];
      const float rstd = stats[m * 8 + pq * 2 + 1];
      const int pix = (hi2 * 2 + p) * HWD + (wi2 * 2 + q);
      float* orow = out + ((size_t)(b * NPIX + pix)) * CDIM;
#pragma unroll
      for (int j = 0; j < 4; ++j) {
        const int col = c0 + wn * 64 + j * 16 + l15;
        orow[col] = rstd * (acc[i][j][r] * WUNSCALE + C1[j] - mu * C2[j]) + C3[j];
      }
    }
  }
}

extern "C" void kernel_launch(void* const* d_in, const int* in_sizes, int n_in,
                              void* d_out, int out_size, void* d_ws,
                              size_t ws_size, hipStream_t stream) {
  const float* x      = (const float*)d_in[0];
  const float* qkv_w  = (const float*)d_in[1];
  const float* qkv_b  = (const float*)d_in[2];
  const float* proj_w = (const float*)d_in[3];
  const float* proj_b = (const float*)d_in[4];
  const float* lp_w   = (const float*)d_in[5];
  const float* lp_b   = (const float*)d_in[6];
  const float* ln_w   = (const float*)d_in[7];
  const float* ln_b   = (const float*)d_in[8];
  float* out = (float*)d_out;

  // workspace layout (float offsets), total ~13.7M floats = 55 MB
  float* ws = (float*)d_ws;
  f16* o16 = (f16*)ws;                        // [12544][384]   4,816,896 f16 (2,408,448 fl)
  float* zreg = ws + 2408448;                 // region: qh,kh,vt
  f16* qh = (f16*)zreg;                       // [128][784][48] 4,816,896 f16
  f16* kh = qh + (size_t)128 * NQ * HD;       // [128][784][48] 4,816,896 f16
  f16* vt = kh + (size_t)128 * NQ * HD;       // [128][48][832] 5,111,808 f16
  float* rest = zreg + 7372800;               // end of q/k/v region
  f16* xp = (f16*)rest;                       // [12544][384]   4,816,896 f16
  f16* qkv_wh = xp + (size_t)12544 * CDIM;    // [1152][384]      442,368 f16
  float* rest2 = rest + 2408448 + 221184;
  f16* wq = (f16*)rest2;                      // [1536][384]    2,359,296 f16 (1,179,648 fl)
  float* cvec = rest2 + 1179648;              // [3][384]           1,152 fl
  float* stats = cvec + 1152;                 // [12544][4][2]    100,352 fl

  // 1) fused prep: pool_cast + w_cast + vt-pad zero + wprep + cvec
  prep_kernel<<<dim3(5952), 256, 0, stream>>>(x, xp, qkv_w, qkv_wh, vt, proj_w,
                                              lp_w, ln_w, lp_b, ln_b, proj_b,
                                              wq, cvec);

  // 2) pooled qkv GEMM (fp16 MFMA, counted-vmcnt pipeline)
  qkv_mfma_kernel<<<dim3(882), 256, 0, stream>>>(xp, qkv_wh, qkv_b, qh, kh, vt);

  // 3) fused flash attention -> fp16 o (128 q-rows/block)
  flash_kernel<<<dim3(7, 128), 256, 0, stream>>>(qh, kh, vt, o16);

  // 4) LN stats
  stats_kernel<<<dim3(3136), 256, 0, stream>>>(o16, lp_w, lp_b, stats);

  // 5) fused upsample+LN+proj GEMM (counted-vmcnt pipeline)
  projfused_kernel<<<dim3(1176), 256, 0, stream>>>(o16, wq, stats, cvec, out);
}

// Round 11
// 238.784 us; speedup vs baseline: 1.2085x; 1.0144x over previous
//
#include <hip/hip_runtime.h>
#include <math.h>

#define CDIM 384
#define NHEADS 8
#define HD 48
#define NQ 784      // 28*28 pooled tokens
#define NQPAD 832   // 13*64, zero-padded k/n extent for V^T
#define NB 16
#define HWD 56
#define NPIX 3136   // 56*56
// 48^-0.5 * log2(e): scores land in exp2 domain, softmax uses raw v_exp_f32
#define QK_SCALE (0.14433756729740643f * 1.4426950408889634f)
#define LN_EPS 1e-5f
#define WSCALE 16.0f     // fold into W_pq to stay clear of f16 denormals
#define WUNSCALE 0.0625f

typedef _Float16 f16;
typedef _Float16 f16x4 __attribute__((ext_vector_type(4)));
typedef _Float16 f16x8 __attribute__((ext_vector_type(8)));
typedef float f32x4 __attribute__((ext_vector_type(4)));

// ---------------- wave/block reduction helpers ----------------
__device__ __forceinline__ float waveSum(float v) {
#pragma unroll
  for (int o = 32; o > 0; o >>= 1) v += __shfl_xor(v, o);
  return v;
}

__device__ __forceinline__ float fast_exp2(float x) {
#if __has_builtin(__builtin_amdgcn_exp2f)
  return __builtin_amdgcn_exp2f(x);
#else
  return __expf(x * 0.6931471805599453f);
#endif
}

// async global->LDS 16B copy (wave-uniform lds base + lane*16 scatter)
__device__ __forceinline__ void gload16(const void* g, void* l) {
  __builtin_amdgcn_global_load_lds(
      (const __attribute__((address_space(1))) void*)g,
      (__attribute__((address_space(3))) void*)l, 16, 0, 0);
}

// chunked-bijective XCD swizzle (m204): dispatch id b -> linear tile id such
// that blocks resident on one XCD (b%8 round-robin) cover a contiguous chunk
// of tiles -> per-XCD L2 working set stays small.
__device__ __forceinline__ int xcd_chunk_lin(int b, int nwg) {
  const int c = b & 7, s = b >> 3;
  const int q = nwg >> 3, r = nwg & 7;
  const int off = (c < r) ? c * (q + 1) : r * (q + 1) + (c - r) * q;
  return off + s;
}

// ---------------- Kernel P: fused prep (launch-count reduction) ----------------
// Branch ladder over independent jobs, all input-only:
//  [0,4704)      pool_cast: pooled-gather x -> fp16 A [12544,384]
//  [4704,5136)   w_cast: qkv_w -> f16
//  [5136,5280)   zero vt pad tokens (784..831 per [bh][d] row; 36864 float4)
//  [5280,5856)   wprep: W_pq = proj_w * lp_w[:,pq] * ln_w * WSCALE -> f16
//  [5856,5952)   cvec: 3 constant vectors (4 j-rows per block, 1 per wave)
__global__ __launch_bounds__(256) void prep_kernel(
    const float* __restrict__ x, f16* __restrict__ xp,
    const float* __restrict__ qkv_w, f16* __restrict__ qkv_wh,
    f16* __restrict__ vt, const float* __restrict__ pw,
    const float* __restrict__ lpw, const float* __restrict__ lnw,
    const float* __restrict__ lp_b, const float* __restrict__ ln_b,
    const float* __restrict__ pb, f16* __restrict__ wq,
    float* __restrict__ cvec) {
  const int blk = blockIdx.x, t = threadIdx.x;
  if (blk < 4704) {
    const int i = (blk * 256 + t) * 4;
    const int row = i / CDIM, col = i % CDIM;
    const int b = row / NQ, qi = row % NQ;
    const int hi = qi / 28, wi = qi % 28;
    const float4 v =
        *(const float4*)(x + ((size_t)(b * NPIX + hi * 112 + wi * 2)) * CDIM + col);
    f16x4 h;
    h.x = (f16)v.x; h.y = (f16)v.y; h.z = (f16)v.z; h.w = (f16)v.w;
    *(f16x4*)(xp + i) = h;
  } else if (blk < 5136) {
    const int i = ((blk - 4704) * 256 + t) * 4;  // < 1152*384
    const float4 v = *(const float4*)(qkv_w + i);
    f16x4 h;
    h.x = (f16)v.x; h.y = (f16)v.y; h.z = (f16)v.z; h.w = (f16)v.w;
    *(f16x4*)(qkv_wh + i) = h;
  } else if (blk < 5280) {
    const int idx = (blk - 5136) * 256 + t;  // < 36864
    const int row = idx / 6, off = idx % 6;  // row < 6144 = 128*48
    float4* p = (float4*)vt + (size_t)row * 104 + 98 + off;  // 832*2B=104 f4
    *p = make_float4(0.f, 0.f, 0.f, 0.f);
  } else if (blk < 5856) {
    const int i4 = ((blk - 5280) * 256 + t) * 4;  // < 1536*384
    const int f = i4 / CDIM, c = i4 % CDIM;
    const int pq = f / CDIM, j = f % CDIM;
    const float4 wv = *(const float4*)(pw + (size_t)j * CDIM + c);
    const float4 ln = *(const float4*)(lnw + c);
    f16x4 h;
    h.x = (f16)(wv.x * lpw[(c + 0) * 4 + pq] * ln.x * WSCALE);
    h.y = (f16)(wv.y * lpw[(c + 1) * 4 + pq] * ln.y * WSCALE);
    h.z = (f16)(wv.z * lpw[(c + 2) * 4 + pq] * ln.z * WSCALE);
    h.w = (f16)(wv.w * lpw[(c + 3) * 4 + pq] * ln.w * WSCALE);
    *(f16x4*)(wq + i4) = h;
  } else {
    const int j = (blk - 5856) * 4 + (t >> 6);  // < 384
    const int lane = t & 63;
    float a1 = 0.f, a2 = 0.f, a3 = 0.f;
#pragma unroll
    for (int i = 0; i < 6; ++i) {
      const int c = lane + i * 64;
      const float wv = pw[(size_t)j * CDIM + c];
      a1 += lp_b[c] * lnw[c] * wv;
      a2 += lnw[c] * wv;
      a3 += ln_b[c] * wv;
    }
    a1 = waveSum(a1);
    a2 = waveSum(a2);
    a3 = waveSum(a3);
    if (lane == 0) {
      cvec[j] = a1;
      cvec[CDIM + j] = a2;
      cvec[2 * CDIM + j] = a3 + pb[j];
    }
  }
}

// ---------------- shared MFMA tile GEMM body (3-deep counted-vmcnt pipeline) ----------------
// C(128x128 tile at m0,n0) = A[M,384] @ B[N,384]^T, fp16 in, fp32 acc.
// Tiles k and k+1 always in flight; at iter k wait s_waitcnt vmcnt(4), raw
// s_barrier, then issue tile k+2 into buf (k-1)%3.
__device__ __forceinline__ void mfma_tile_gemm_pipe(
    const f16* __restrict__ A, const f16* __restrict__ B, int m0, int n0,
    f32x4 (&acc)[4][4], f16* As, f16* Bs) {
  const int t = threadIdx.x;
  const int lane = t & 63, w = t >> 6;
  const int wm = w >> 1, wn = w & 1;
  const int l15 = lane & 15, l4 = lane >> 4;
  const int rowS = t >> 2;
  const int kb = (t & 3) * 16;
  char* AsB = (char*)As;
  char* BsB = (char*)Bs;
  const char* Ag = (const char*)A + ((size_t)(m0 + rowS) * CDIM) * 2 + kb;
  const char* Bg = (const char*)B + ((size_t)(n0 + rowS) * CDIM) * 2 + kb;
  const size_t row64 = (size_t)64 * CDIM * 2;

#define ISSUE(kk)                                           \
  do {                                                      \
    const int bofs = ((kk) % 3) * 8192;                     \
    const char* Ag2 = Ag + (size_t)(kk) * 64;               \
    const char* Bg2 = Bg + (size_t)(kk) * 64;               \
    gload16(Ag2, AsB + bofs + t * 16);                      \
    gload16(Ag2 + row64, AsB + bofs + 4096 + t * 16);       \
    gload16(Bg2, BsB + bofs + t * 16);                      \
    gload16(Bg2 + row64, BsB + bofs + 4096 + t * 16);       \
  } while (0)

  ISSUE(0);
  ISSUE(1);

#pragma unroll
  for (int k = 0; k < 12; ++k) {
    if (k < 11)
      asm volatile("s_waitcnt vmcnt(4)" ::: "memory");
    else
      asm volatile("s_waitcnt vmcnt(0)" ::: "memory");
    __builtin_amdgcn_s_barrier();
    __builtin_amdgcn_sched_barrier(0);
    if (k + 2 < 12) ISSUE(k + 2);
    const char* Ab = AsB + (k % 3) * 8192;
    const char* Bb = BsB + (k % 3) * 8192;
    f16x8 af[4], bf[4];
#pragma unroll
    for (int i = 0; i < 4; ++i)
      af[i] = *(const f16x8*)(Ab + ((wm * 64 + i * 16 + l15) * 64 + l4 * 16));
#pragma unroll
    for (int j = 0; j < 4; ++j)
      bf[j] = *(const f16x8*)(Bb + ((wn * 64 + j * 16 + l15) * 64 + l4 * 16));
#pragma unroll
    for (int i = 0; i < 4; ++i)
#pragma unroll
      for (int j = 0; j < 4; ++j)
        acc[i][j] =
            __builtin_amdgcn_mfma_f32_16x16x32_f16(af[i], bf[j], acc[i][j], 0, 0, 0);
  }
#undef ISSUE
}

// ---------------- Kernel A: QKV GEMM (fp16 MFMA) ----------------
// 1D grid 882 = 98 m-tiles x 9 n-tiles, XCD-chunk swizzled. Each n-tile lies
// in exactly one of q/k/v. Epilogue transposes the 128x128 result through LDS
// so all global stores are 16B vectors.
__global__ __launch_bounds__(256) void qkv_mfma_kernel(
    const f16* __restrict__ xp, const f16* __restrict__ wh,
    const float* __restrict__ qkv_b, f16* __restrict__ qh,
    f16* __restrict__ kh, f16* __restrict__ vt) {
  __shared__ union SU {
    struct { f16 As[3 * 128 * 32]; f16 Bs[3 * 128 * 32]; } s;  // 48 KB
    f16 Tr[128][136];                                          // 34 KB
  } u;
  const int lin = xcd_chunk_lin(blockIdx.x, 882);
  const int m0 = (lin / 9) * 128, n0 = (lin % 9) * 128;
  f32x4 acc[4][4] = {};
  mfma_tile_gemm_pipe(xp, wh, m0, n0, acc, u.s.As, u.s.Bs);

  const int t = threadIdx.x, lane = t & 63, w = t >> 6;
  const int wm = w >> 1, wn = w & 1;
  const int l15 = lane & 15, l4 = lane >> 4;
  const int sec = n0 / CDIM;  // 0=q, 1=k, 2=v (block-uniform)
  const float scl = (sec == 0) ? QK_SCALE : 1.f;

  __syncthreads();  // all LDS reads of As/Bs complete before aliasing as Tr

  if (sec < 2) {
    // Tr[qi_local][f_local]
#pragma unroll
    for (int j = 0; j < 4; ++j) {
      const int fl_ = wn * 64 + j * 16 + l15;
      const float bias = qkv_b[n0 + fl_];
#pragma unroll
      for (int i = 0; i < 4; ++i)
#pragma unroll
        for (int r = 0; r < 4; ++r)
          u.Tr[wm * 64 + i * 16 + l4 * 4 + r][fl_] =
              (f16)((acc[i][j][r] + bias) * scl);
    }
  } else {
    // Tr[f_local][qi_local]
#pragma unroll
    for (int j = 0; j < 4; ++j) {
      const int fl_ = wn * 64 + j * 16 + l15;
      const float bias = qkv_b[n0 + fl_];
#pragma unroll
      for (int i = 0; i < 4; ++i)
#pragma unroll
        for (int r = 0; r < 4; ++r)
          u.Tr[fl_][wm * 64 + i * 16 + l4 * 4 + r] = (f16)(acc[i][j][r] + bias);
    }
  }
  __syncthreads();

  // read back 16B units, store wide. 2048 units, 8 per thread.
#pragma unroll
  for (int c = 0; c < 8; ++c) {
    const int v = c * 256 + t;
    const int rr = v >> 4, u16 = v & 15;
    if (sec < 2) {
      const int qi_l = rr, f_l = u16 * 8;
      const int fr = n0 + f_l - sec * CDIM;
      const int hh = fr / HD, d = fr - hh * HD;
      const int mm = m0 + qi_l, b = mm / NQ, tok = mm - b * NQ;
      f16* dst = (sec == 0 ? qh : kh) +
                 ((size_t)(b * NHEADS + hh) * NQ + tok) * HD + d;
      *(f16x8*)dst = *(const f16x8*)&u.Tr[qi_l][f_l];
    } else {
      const int f_l = rr, qi0 = u16 * 8;
      const int fr = n0 + f_l - 2 * CDIM;
      const int hh = fr / HD, d = fr - hh * HD;
      const int mm = m0 + qi0, b = mm / NQ, tok = mm - b * NQ;
      f16* dst = vt + ((size_t)(b * NHEADS + hh) * HD + d) * NQPAD + tok;
      *(f16x8*)dst = *(const f16x8*)&u.Tr[f_l][qi0];
    }
  }
}

// ---------------- Kernel B: fused flash attention (no-max softmax) ----------------
// R8-proven body (242.2us total). Only change: 1D grid 896, XCD-grouped —
// block B -> xcd c=B&7 owns bh c*16..c*16+15 (K/V working set 2.4MB ->
// L2-resident per XCD). Mapping bijective: 8 x 16 x 7 = 896.
__global__ __launch_bounds__(256) void flash_kernel(
    const f16* __restrict__ qh, const f16* __restrict__ kh,
    const f16* __restrict__ vt, f16* __restrict__ o16) {
  __shared__ f16 PQ[128 * 72];     // 18432 B: Qs[128][72]; recycled as Ps[4][32][68]
  __shared__ f16 Ks[64][72];       // 9216 B
  __shared__ f16 Vts[48][72];      // 6912 B

  f16 (*Qs)[72] = (f16(*)[72])PQ;
  f16 (*Ps)[32][68] = (f16(*)[32][68])PQ;

  const int t = threadIdx.x;
  const int lane = t & 63, w = t >> 6;
  const int quad = lane >> 4, l15 = lane & 15;
  const int B = blockIdx.x;                 // 0..895
  const int bh = (B & 7) * 16 + (B >> 3) / 7;
  const int q0 = ((B >> 3) % 7) * 128;

  const f16* qg = qh + (size_t)bh * NQ * HD;
  const f16* kg = kh + (size_t)bh * NQ * HD;
  const f16* vg = vt + (size_t)bh * HD * NQPAD;

  // ---- zero k-pad cols 48..63 of Qs (256 units) and Ks (128 units) ----
  {
    const f16x8 z8 = {};
    *(f16x8*)&Qs[t >> 1][48 + (t & 1) * 8] = z8;
    if (t < 128) *(f16x8*)&Ks[t >> 1][48 + (t & 1) * 8] = z8;
  }

  // ---- stage Q tile: 128 rows x 48 cols (6 segs of 16B) ----
#pragma unroll
  for (int c = 0; c < 3; ++c) {
    const int u = t + c * 256;  // < 768
    const int row = u / 6, seg = u % 6;
    const int gr = min(q0 + row, NQ - 1);
    *(f16x8*)&Qs[row][seg * 8] =
        *(const f16x8*)(qg + (size_t)gr * HD + seg * 8);
  }
  __syncthreads();

  // ---- hoist Q fragments (Qs LDS is recycled as Ps after this) ----
  f16x8 qf0[2], qf1[2];
#pragma unroll
  for (int qa = 0; qa < 2; ++qa) {
    const int row = w * 32 + qa * 16 + l15;
    qf0[qa] = *(const f16x8*)&Qs[row][quad * 8];
    qf1[qa] = *(const f16x8*)&Qs[row][32 + quad * 8];
  }

  // ---- staging plan: 768 16B-units per K/V tile = 3 per thread ----
  const f16* gp[3];
  f16* lp[3];
  int step[3];
#pragma unroll
  for (int c = 0; c < 3; ++c) {
    const int u = t + c * 256;
    if (u < 384) {  // K: 64 rows x 6 segs (cols 0..47)
      const int row = u / 6, seg = u % 6;
      gp[c] = kg + (size_t)row * HD + seg * 8;
      lp[c] = &Ks[row][seg * 8];
      step[c] = 64 * HD;
    } else {        // V^T: 48 rows x 8 segs
      const int uv = u - 384;
      const int row = uv >> 3, seg = uv & 7;
      gp[c] = vg + (size_t)row * NQPAD + seg * 8;
      lp[c] = &Vts[row][seg * 8];
      step[c] = 64;
    }
  }

  // prologue: issue tile 0 loads
  f16x8 rg[3];
#pragma unroll
  for (int c = 0; c < 3; ++c) {
    rg[c] = *(const f16x8*)gp[c];
    gp[c] += step[c];
  }

  f32x4 accO[2][3] = {};
  float l_[2][4] = {};

  for (int kt = 0; kt < 13; ++kt) {
    // commit staged tile kt to LDS (cols 0..47 only; pads stay zero)
#pragma unroll
    for (int c = 0; c < 3; ++c) *(f16x8*)lp[c] = rg[c];
    __syncthreads();
    // issue tile kt+1 loads; HBM latency hides under compute below
    if (kt < 12) {
#pragma unroll
      for (int c = 0; c < 3; ++c) {
        rg[c] = *(const f16x8*)gp[c];
        gp[c] += step[c];
      }
    }

    // ---- QK^T (k=0..63, pad zeros) fused with exp2 + row-sum + P store ----
    const bool last = (kt == 12);
#pragma unroll
    for (int j = 0; j < 4; ++j) {
      const f16x8 b0 = *(const f16x8*)&Ks[j * 16 + l15][quad * 8];
      const f16x8 b1 = *(const f16x8*)&Ks[j * 16 + l15][32 + quad * 8];
      f32x4 z0 = {}, z1 = {};
      z0 = __builtin_amdgcn_mfma_f32_16x16x32_f16(qf0[0], b0, z0, 0, 0, 0);
      const f32x4 sj0 = __builtin_amdgcn_mfma_f32_16x16x32_f16(qf1[0], b1, z0, 0, 0, 0);
      z1 = __builtin_amdgcn_mfma_f32_16x16x32_f16(qf0[1], b0, z1, 0, 0, 0);
      const f32x4 sj1 = __builtin_amdgcn_mfma_f32_16x16x32_f16(qf1[1], b1, z1, 0, 0, 0);
      const bool msk = last && (j >= 1);  // keys >= 784
#pragma unroll
      for (int r = 0; r < 4; ++r) {
        const float p0 = msk ? 0.f : fast_exp2(sj0[r]);
        const float p1 = msk ? 0.f : fast_exp2(sj1[r]);
        l_[0][r] += p0;
        l_[1][r] += p1;
        Ps[w][quad * 4 + r][j * 16 + l15] = (f16)p0;
        Ps[w][16 + quad * 4 + r][j * 16 + l15] = (f16)p1;
      }
    }

    // ---- P fragments (8B-aligned b64 pairs; stride 68 spreads banks) ----
    f16x8 ap0[2], ap1[2];
#pragma unroll
    for (int qa = 0; qa < 2; ++qa) {
      const int row = qa * 16 + l15;
      const f16x4 a0 = *(const f16x4*)&Ps[w][row][quad * 8];
      const f16x4 a1 = *(const f16x4*)&Ps[w][row][quad * 8 + 4];
      const f16x4 a2 = *(const f16x4*)&Ps[w][row][32 + quad * 8];
      const f16x4 a3 = *(const f16x4*)&Ps[w][row][32 + quad * 8 + 4];
      ap0[qa] = __builtin_shufflevector(a0, a1, 0, 1, 2, 3, 4, 5, 6, 7);
      ap1[qa] = __builtin_shufflevector(a2, a3, 0, 1, 2, 3, 4, 5, 6, 7);
    }

    // ---- PV ----
#pragma unroll
    for (int jn = 0; jn < 3; ++jn) {
      const f16x8 v0 = *(const f16x8*)&Vts[jn * 16 + l15][quad * 8];
      const f16x8 v1 = *(const f16x8*)&Vts[jn * 16 + l15][32 + quad * 8];
#pragma unroll
      for (int qa = 0; qa < 2; ++qa) {
        accO[qa][jn] =
            __builtin_amdgcn_mfma_f32_16x16x32_f16(ap0[qa], v0, accO[qa][jn], 0, 0, 0);
        accO[qa][jn] =
            __builtin_amdgcn_mfma_f32_16x16x32_f16(ap1[qa], v1, accO[qa][jn], 0, 0, 0);
      }
    }
    __syncthreads();
  }

  // ---- normalize + store ----
  const int b = bh >> 3, hh = bh & 7;
#pragma unroll
  for (int qa = 0; qa < 2; ++qa) {
#pragma unroll
    for (int r = 0; r < 4; ++r) {
      float rs = l_[qa][r];
      rs += __shfl_xor(rs, 1);
      rs += __shfl_xor(rs, 2);
      rs += __shfl_xor(rs, 4);
      rs += __shfl_xor(rs, 8);
      const int qrow = q0 + w * 32 + qa * 16 + quad * 4 + r;
      if (qrow < NQ) {
        const float inv = 1.f / rs;
#pragma unroll
        for (int jn = 0; jn < 3; ++jn)
          o16[((size_t)(b * NQ + qrow)) * CDIM + hh * HD + jn * 16 + l15] =
              (f16)(accO[qa][jn][r] * inv);
      }
    }
  }
}

// ---------------- Kernel C1: per-row LN stats for the 4 upsample phases ----------------
__global__ __launch_bounds__(256) void stats_kernel(
    const f16* __restrict__ o16, const float* __restrict__ lp_w,
    const float* __restrict__ lp_b, float* __restrict__ stats) {
  const int m = blockIdx.x * 4 + (threadIdx.x >> 6);
  const int lane = threadIdx.x & 63;
  float s[4] = {}, ss[4] = {};
#pragma unroll
  for (int i = 0; i < 6; ++i) {
    const int c = lane + i * 64;
    const float ov = (float)o16[(size_t)m * CDIM + c];
    const float4 w4 = *(const float4*)(lp_w + c * 4);
    const float bb = lp_b[c];
    const float u0 = ov * w4.x + bb;
    const float u1 = ov * w4.y + bb;
    const float u2 = ov * w4.z + bb;
    const float u3 = ov * w4.w + bb;
    s[0] += u0; ss[0] += u0 * u0;
    s[1] += u1; ss[1] += u1 * u1;
    s[2] += u2; ss[2] += u2 * u2;
    s[3] += u3; ss[3] += u3 * u3;
  }
#pragma unroll
  for (int pq = 0; pq < 4; ++pq) {
    s[pq] = waveSum(s[pq]);
    ss[pq] = waveSum(ss[pq]);
  }
  if (lane < 4) {
    const float mu = s[lane] * (1.f / CDIM);
    const float var = ss[lane] * (1.f / CDIM) - mu * mu;
    stats[m * 8 + lane * 2] = mu;
    stats[m * 8 + lane * 2 + 1] = rsqrtf(var + LN_EPS);
  }
}

// ---------------- Kernel D: fused upsample+LN+proj GEMM ----------------
// G = o16 @ wq^T  (M=12544, N=1536, K=384); out row (m,pq) -> pixel scatter.
// 1D grid 1176 = 98 m-tiles x 12 n-tiles, XCD-chunk swizzled.
__global__ __launch_bounds__(256) void projfused_kernel(
    const f16* __restrict__ o16, const f16* __restrict__ wq,
    const float* __restrict__ stats, const float* __restrict__ cvec,
    float* __restrict__ out) {
  __shared__ f16 As[3 * 128 * 32];
  __shared__ f16 Bs[3 * 128 * 32];
  const int lin = xcd_chunk_lin(blockIdx.x, 1176);
  const int m0 = (lin / 12) * 128, n0 = (lin % 12) * 128;
  f32x4 acc[4][4] = {};
  mfma_tile_gemm_pipe(o16, wq, m0, n0, acc, As, Bs);

  const int t = threadIdx.x, lane = t & 63, w = t >> 6;
  const int wm = w >> 1, wn = w & 1;
  const int l15 = lane & 15, l4 = lane >> 4;
  const int pq = n0 / CDIM;  // uniform per block
  const int p = pq >> 1, q = pq & 1;
  const int c0 = n0 - pq * CDIM;

  float C1[4], C2[4], C3[4];
#pragma unroll
  for (int j = 0; j < 4; ++j) {
    const int col = c0 + wn * 64 + j * 16 + l15;
    C1[j] = cvec[col];
    C2[j] = cvec[CDIM + col];
    C3[j] = cvec[2 * CDIM + col];
  }

#pragma unroll
  for (int i = 0; i < 4; ++i) {
#pragma unroll
    for (int r = 0; r < 4; ++r) {
      const int m = m0 + wm * 64 + i * 16 + l4 * 4 + r;
      const int b = m / NQ, n = m % NQ;
      const int hi2 = n / 28, wi2 = n % 28;
      const float mu = stats[m * 8 + pq * 2];
      const float rstd = stats[m * 8 + pq * 2 + 1];
      const int pix = (hi2 * 2 + p) * HWD + (wi2 * 2 + q);
      float* orow = out + ((size_t)(b * NPIX + pix)) * CDIM;
#pragma unroll
      for (int j = 0; j < 4; ++j) {
        const int col = c0 + wn * 64 + j * 16 + l15;
        orow[col] = rstd * (acc[i][j][r] * WUNSCALE + C1[j] - mu * C2[j]) + C3[j];
      }
    }
  }
}

extern "C" void kernel_launch(void* const* d_in, const int* in_sizes, int n_in,
                              void* d_out, int out_size, void* d_ws,
                              size_t ws_size, hipStream_t stream) {
  const float* x      = (const float*)d_in[0];
  const float* qkv_w  = (const float*)d_in[1];
  const float* qkv_b  = (const float*)d_in[2];
  const float* proj_w = (const float*)d_in[3];
  const float* proj_b = (const float*)d_in[4];
  const float* lp_w   = (const float*)d_in[5];
  const float* lp_b   = (const float*)d_in[6];
  const float* ln_w   = (const float*)d_in[7];
  const float* ln_b   = (const float*)d_in[8];
  float* out = (float*)d_out;

  // workspace layout (float offsets), total ~13.7M floats = 55 MB
  float* ws = (float*)d_ws;
  f16* o16 = (f16*)ws;                        // [12544][384]   4,816,896 f16 (2,408,448 fl)
  float* zreg = ws + 2408448;                 // region: qh,kh,vt
  f16* qh = (f16*)zreg;                       // [128][784][48] 4,816,896 f16
  f16* kh = qh + (size_t)128 * NQ * HD;       // [128][784][48] 4,816,896 f16
  f16* vt = kh + (size_t)128 * NQ * HD;       // [128][48][832] 5,111,808 f16
  float* rest = zreg + 7372800;               // end of q/k/v region
  f16* xp = (f16*)rest;                       // [12544][384]   4,816,896 f16
  f16* qkv_wh = xp + (size_t)12544 * CDIM;    // [1152][384]      442,368 f16
  float* rest2 = rest + 2408448 + 221184;
  f16* wq = (f16*)rest2;                      // [1536][384]    2,359,296 f16 (1,179,648 fl)
  float* cvec = rest2 + 1179648;              // [3][384]           1,152 fl
  float* stats = cvec + 1152;                 // [12544][4][2]    100,352 fl

  // 1) fused prep: pool_cast + w_cast + vt-pad zero + wprep + cvec
  prep_kernel<<<dim3(5952), 256, 0, stream>>>(x, xp, qkv_w, qkv_wh, vt, proj_w,
                                              lp_w, ln_w, lp_b, ln_b, proj_b,
                                              wq, cvec);

  // 2) pooled qkv GEMM (fp16 MFMA, counted-vmcnt pipeline)
  qkv_mfma_kernel<<<dim3(882), 256, 0, stream>>>(xp, qkv_wh, qkv_b, qh, kh, vt);

  // 3) fused flash attention -> fp16 o (XCD-grouped 1D grid, R8 body)
  flash_kernel<<<dim3(896), 256, 0, stream>>>(qh, kh, vt, o16);

  // 4) LN stats
  stats_kernel<<<dim3(3136), 256, 0, stream>>>(o16, lp_w, lp_b, stats);

  // 5) fused upsample+LN+proj GEMM (counted-vmcnt pipeline)
  projfused_kernel<<<dim3(1176), 256, 0, stream>>>(o16, wq, stats, cvec, out);
}